// Round 8
// baseline (2235.988 us; speedup 1.0000x reference)
//
#include <hip/hip_runtime.h>
#include <hip/hip_bf16.h>
#include <hip/hip_fp16.h>
#include <type_traits>
#include <utility>

// FaceModel: N=500000 nodes, E=3000000 edges, F=128. fp32 in/out, f16 internal.
// R8: fuse GEMM chains between gather boundaries (weight time-multiplexing in
// one 32KB LDS buffer + per-wave 16x128 f16 LDS tile):
//   fusedB = g1(dual) + s1_w0 + s1_w1 + s1_w2          (saves ~750MB traffic)
//   fusedC = ff-recompute + g2(dual) + s2_0(dual) + s2_1 + final (~870MB)
// fill/hist batched 4 edges/thread (int4) to fix MLP (was 260us, 1 edge/thr).
// wT moves to ws tail slack (fusedC reads weights while writing d_out).
// cur stays in d_out (consumed by gather2 before first d_out write).

#define NROWS 500000
#define NEDGE 3000000
#define SCAN_CHUNK 1024
#define NBLK_SCAN ((NROWS + SCAN_CHUNK - 1) / SCAN_CHUNK)   // 489

typedef unsigned short u16;
using short8 = __attribute__((ext_vector_type(8))) short;
using half8  = __attribute__((ext_vector_type(8))) _Float16;
using f32x4  = __attribute__((ext_vector_type(4))) float;

__device__ __forceinline__ u16 f2h_bits(float f) {
  _Float16 h = (_Float16)f;
  return __builtin_bit_cast(u16, h);
}
__device__ __forceinline__ float h2f(u16 b) {
  return (float)__builtin_bit_cast(_Float16, b);
}
__device__ __forceinline__ float eluf(float x) { return x > 0.0f ? x : expm1f(x); }

// --- f16 packed atomic add with fallback (scatter fallback path only) ------
template <typename T, typename = void> struct HasUnsafeAdd : std::false_type {};
template <typename T>
struct HasUnsafeAdd<T, std::void_t<decltype(unsafeAtomicAdd(
    std::declval<T*>(), std::declval<T>()))>> : std::true_type {};
template <bool HAS> struct AtomAdd;
template <> struct AtomAdd<true> {
  template <class T> __device__ static void go(T* p, T v) { unsafeAtomicAdd(p, v); }
};
template <> struct AtomAdd<false> {
  template <class T> __device__ static void go(T* p, T v) {
    unsigned* up = reinterpret_cast<unsigned*>(p);
    unsigned old = *up;
    while (true) {
      unsigned assumed = old;
      T cur = __builtin_bit_cast(T, assumed);
      T nw = __hadd2(cur, v);
      old = atomicCAS(up, assumed, __builtin_bit_cast(unsigned, nw));
      if (old == assumed) break;
    }
  }
};
__device__ __forceinline__ void atomAddH2(__half2* p, __half2 v) {
  AtomAdd<HasUnsafeAdd<__half2>::value>::go(p, v);
}

// ---------------------------------------------------------------------------
// Weight transpose fp32 -> f16 stash: out[slot][n*128+k] = W[k][n].
// Slots: 0 mf_w1, 1 g1_rel, 2 g1_root, 3 s1_w0, 4 s1_w1, 5 s1_w2,
//        6 g2_rel, 7 g2_root, 8 s2_w0[0:128], 9 s2_w0[128:256], 10 s2_w1
// ---------------------------------------------------------------------------
__global__ __launch_bounds__(256) void transpose_w(
    const float* p0, const float* p1, const float* p2, const float* p3,
    const float* p4, const float* p5, const float* p6, const float* p7,
    const float* p8, const float* p10, u16* dst)
{
  const float* src = p0; int eoff = 0;
  switch (blockIdx.y) {
    case 1: src = p1; break;  case 2: src = p2; break;
    case 3: src = p3; break;  case 4: src = p4; break;
    case 5: src = p5; break;  case 6: src = p6; break;
    case 7: src = p7; break;  case 8: src = p8; break;
    case 9: src = p8; eoff = 16384; break;
    case 10: src = p10; break;
    default: break;
  }
  u16* out = dst + (size_t)blockIdx.y * 16384;
  for (int i = threadIdx.x + blockIdx.x * 256; i < 16384; i += 2048) {
    int n = i >> 7, k = i & 127;
    out[i] = f2h_bits(src[eoff + k * 128 + n]);
  }
}

// ---------------------------------------------------------------------------
// CSR build. cur: counts -> start offsets (scanC) -> end offsets (fill).
// ---------------------------------------------------------------------------
__global__ __launch_bounds__(256) void hist_kernel(const int* __restrict__ ei,
                                                   int* __restrict__ cur) {
  int base = (blockIdx.x * 256 + threadIdx.x) * 4;
  if (base >= NEDGE) return;
  int4 d4 = *reinterpret_cast<const int4*>(ei + NEDGE + base);
  atomicAdd(&cur[d4.x], 1);
  atomicAdd(&cur[d4.y], 1);
  atomicAdd(&cur[d4.z], 1);
  atomicAdd(&cur[d4.w], 1);
}

__global__ __launch_bounds__(256) void scanA(const int* __restrict__ cur,
                                             int* __restrict__ bsum) {
  __shared__ int sdata[256];
  int b = blockIdx.x, tid = threadIdx.x;
  int base = b * SCAN_CHUNK + tid * 4;
  int s = 0;
#pragma unroll
  for (int t = 0; t < 4; ++t) {
    int i = base + t;
    if (i < NROWS) s += cur[i];
  }
  sdata[tid] = s;
  __syncthreads();
  for (int off = 128; off > 0; off >>= 1) {
    if (tid < off) sdata[tid] += sdata[tid + off];
    __syncthreads();
  }
  if (tid == 0) bsum[b] = sdata[0];
}

__global__ __launch_bounds__(512) void scanB(int* bsum) {   // in-place -> excl
  __shared__ int sdata[512];
  int tid = threadIdx.x;
  int v = (tid < NBLK_SCAN) ? bsum[tid] : 0;
  sdata[tid] = v;
  __syncthreads();
  for (int off = 1; off < 512; off <<= 1) {
    int val = (tid >= off) ? sdata[tid - off] : 0;
    __syncthreads();
    sdata[tid] += val;
    __syncthreads();
  }
  if (tid < NBLK_SCAN) bsum[tid] = sdata[tid] - v;
}

__global__ __launch_bounds__(256) void scanC(const int* __restrict__ boff,
                                             int* __restrict__ cur) {
  __shared__ int sdata[256];
  int b = blockIdx.x, tid = threadIdx.x;
  int base = b * SCAN_CHUNK + tid * 4;
  int v[4]; int s = 0;
#pragma unroll
  for (int t = 0; t < 4; ++t) {
    int i = base + t;
    v[t] = (i < NROWS) ? cur[i] : 0;
    s += v[t];
  }
  sdata[tid] = s;
  __syncthreads();
  for (int off = 1; off < 256; off <<= 1) {
    int val = (tid >= off) ? sdata[tid - off] : 0;
    __syncthreads();
    sdata[tid] += val;
    __syncthreads();
  }
  int excl = sdata[tid] - s + boff[b];
#pragma unroll
  for (int t = 0; t < 4; ++t) {
    int i = base + t;
    if (i < NROWS) cur[i] = excl;
    excl += v[t];
  }
}

__global__ __launch_bounds__(256) void fill_kernel(const int* __restrict__ ei,
                                                   int* __restrict__ cur,
                                                   int* __restrict__ adj) {
  int base = (blockIdx.x * 256 + threadIdx.x) * 4;
  if (base >= NEDGE) return;
  int4 d4 = *reinterpret_cast<const int4*>(ei + NEDGE + base);
  int4 s4 = *reinterpret_cast<const int4*>(ei + base);
  int p0 = atomicAdd(&cur[d4.x], 1);
  int p1 = atomicAdd(&cur[d4.y], 1);
  int p2 = atomicAdd(&cur[d4.z], 1);
  int p3 = atomicAdd(&cur[d4.w], 1);
  adj[p0] = s4.x; adj[p1] = s4.y; adj[p2] = s4.z; adj[p3] = s4.w;
}

// ---------------------------------------------------------------------------
// Gather segment-sum: wave per node, 8 rows batched (MLP), fp32 accumulate.
// ---------------------------------------------------------------------------
__global__ __launch_bounds__(256) void gather_agg(
    const u16* __restrict__ x, const int* __restrict__ cend,
    const int* __restrict__ adj, u16* __restrict__ agg)
{
  int wv = threadIdx.x >> 6, lane = threadIdx.x & 63;
  long node = (long)blockIdx.x * 4 + wv;
  if (node >= NROWS) return;
  int beg = (node == 0) ? 0 : cend[node - 1];
  int end = cend[node];
  float a0 = 0.f, a1 = 0.f;
  for (int j = beg; j < end; j += 8) {
    int take = end - j;
    if (take > 8) take = 8;
    int srcv = (lane < take) ? adj[j + lane] : 0;
    unsigned hb[8];
#pragma unroll
    for (int t = 0; t < 8; ++t) {
      if (t < take) {
        int src = __shfl(srcv, t);
        hb[t] = *reinterpret_cast<const unsigned*>(x + (long)src * 128 + lane * 2);
      }
    }
#pragma unroll
    for (int t = 0; t < 8; ++t) {
      if (t < take) {
        __half2 h = __builtin_bit_cast(__half2, hb[t]);
        a0 += (float)h.x;
        a1 += (float)h.y;
      }
    }
  }
  __half2 r;
  r.x = __float2half(a0);
  r.y = __float2half(a1);
  *reinterpret_cast<__half2*>(agg + node * 128 + lane * 2) = r;
}

// ---------------------------------------------------------------------------
// Atomic scatter (fallback path only).
// ---------------------------------------------------------------------------
__global__ __launch_bounds__(256) void scatter_kernel(
    const u16* __restrict__ x, const int* __restrict__ ei,
    __half2* __restrict__ agg)
{
  int gtid = blockIdx.x * 256 + threadIdx.x;
  int wid = gtid >> 6, lane = gtid & 63;
  int nw = gridDim.x * 4;
  for (int e = wid; e < NEDGE; e += nw) {
    int s = ei[e];
    int d = ei[NEDGE + e];
    __half2 h = *reinterpret_cast<const __half2*>(x + (long)s * 128 + lane * 2);
    atomAddH2(agg + (long)d * 64 + lane, h);
  }
}

// ---------------------------------------------------------------------------
// MFMA helpers: swizzled weight staging + fused-chain building blocks.
// ---------------------------------------------------------------------------
__device__ __forceinline__ void load_w_swz(const u16* Wt, short* ws, int tid) {
  for (int c = tid; c < 2048; c += 256) {
    int n = c >> 4, kb = c & 15;
    short8 v = *reinterpret_cast<const short8*>(Wt + n * 128 + kb * 8);
    *reinterpret_cast<short8*>(ws + ((n << 4) | (kb ^ (n & 15))) * 8) = v;
  }
}
__device__ __forceinline__ half8 read_b_swz(const short* ws, int col, int kb) {
  short8 v = *reinterpret_cast<const short8*>(ws + ((col << 4) | (kb ^ (col & 15))) * 8);
  return __builtin_bit_cast(half8, v);
}
// accumulate X[16 rows]@W into acc; X from global (guarded by active)
__device__ __forceinline__ void gemm_global(f32x4* acc, const u16* X, long arow,
                                            bool active, const short* wbuf,
                                            int nl, int q) {
#pragma unroll
  for (int s = 0; s < 4; ++s) {
    int kofs = s * 32 + q * 8, kb = (s << 2) | q;
    half8 a = half8{0,0,0,0,0,0,0,0};
    if (active)
      a = __builtin_bit_cast(half8,
          *reinterpret_cast<const short8*>(X + arow * 128 + kofs));
#pragma unroll
    for (int c = 0; c < 8; ++c) {
      half8 b = read_b_swz(wbuf, (c << 4) | nl, kb);
      acc[c] = __builtin_amdgcn_mfma_f32_16x16x32_f16(a, b, acc[c], 0, 0, 0);
    }
  }
}
// accumulate tile[16 rows]@W into acc; mytile = wave's 16x136 region
__device__ __forceinline__ void gemm_tile(f32x4* acc, const short* mytile,
                                          const short* wbuf, int nl, int q) {
#pragma unroll
  for (int s = 0; s < 4; ++s) {
    int kofs = s * 32 + q * 8, kb = (s << 2) | q;
    half8 a = __builtin_bit_cast(half8,
        *reinterpret_cast<const short8*>(&mytile[nl * 136 + kofs]));
#pragma unroll
    for (int c = 0; c < 8; ++c) {
      half8 b = read_b_swz(wbuf, (c << 4) | nl, kb);
      acc[c] = __builtin_amdgcn_mfma_f32_16x16x32_f16(a, b, acc[c], 0, 0, 0);
    }
  }
}
// acc + bias (+ELU) -> wave tile
template<bool ACT>
__device__ __forceinline__ void epi_tile(const f32x4* acc, const float* bias,
                                         short* mytile, int nl, int q) {
#pragma unroll
  for (int c = 0; c < 8; ++c) {
    float bv = bias[(c << 4) | nl];
#pragma unroll
    for (int r = 0; r < 4; ++r) {
      float o = acc[c][r] + bv;
      if constexpr (ACT) o = eluf(o);
      mytile[(q * 4 + r) * 136 + ((c << 4) | nl)] = (short)f2h_bits(o);
    }
  }
}
__device__ __forceinline__ void zero_acc(f32x4* acc) {
#pragma unroll
  for (int c = 0; c < 8; ++c) acc[c] = f32x4{0.f, 0.f, 0.f, 0.f};
}

// ---------------------------------------------------------------------------
// fusedB: h = elu(...elu(elu(agg@g1_rel + g1b + ff@g1_root) @ s1w0+b)...@ s1w2+b)
// Writes h in-place over ff (A). 256 thr, 64 rows/block, 16 rows/wave.
// ---------------------------------------------------------------------------
__global__ __launch_bounds__(256) void fusedB(
    const u16* __restrict__ G, u16* A, const u16* __restrict__ wT,
    const float* __restrict__ g1b, const float* __restrict__ s1b0,
    const float* __restrict__ s1b1, const float* __restrict__ s1b2)
{
  __shared__ __align__(16) short wbuf[16384];
  __shared__ __align__(16) short tile[64 * 136];
  int tid = threadIdx.x;
  int wv = tid >> 6, lane = tid & 63, nl = lane & 15, q = lane >> 4;
  long r0 = (long)blockIdx.x * 64 + wv * 16;
  bool active = r0 < NROWS;
  long arow = r0 + nl;
  short* mytile = &tile[(wv * 16) * 136];

  f32x4 acc[8];
  zero_acc(acc);

  load_w_swz(wT + 1 * 16384, wbuf, tid); __syncthreads();     // g1_rel
  gemm_global(acc, G, arow, active, wbuf, nl, q);
  __syncthreads();
  load_w_swz(wT + 2 * 16384, wbuf, tid); __syncthreads();     // g1_root
  gemm_global(acc, A, arow, active, wbuf, nl, q);
  epi_tile<true>(acc, g1b, mytile, nl, q);
  __syncthreads();
  load_w_swz(wT + 3 * 16384, wbuf, tid); __syncthreads();     // s1_w0
  zero_acc(acc);
  gemm_tile(acc, mytile, wbuf, nl, q);
  epi_tile<true>(acc, s1b0, mytile, nl, q);
  __syncthreads();
  load_w_swz(wT + 4 * 16384, wbuf, tid); __syncthreads();     // s1_w1
  zero_acc(acc);
  gemm_tile(acc, mytile, wbuf, nl, q);
  epi_tile<true>(acc, s1b1, mytile, nl, q);
  __syncthreads();
  load_w_swz(wT + 5 * 16384, wbuf, tid); __syncthreads();     // s1_w2
  zero_acc(acc);
  gemm_tile(acc, mytile, wbuf, nl, q);
  if (active) {
#pragma unroll
    for (int c = 0; c < 8; ++c) {
      float bv = s1b2[(c << 4) | nl];
#pragma unroll
      for (int r = 0; r < 4; ++r)
        A[(r0 + q * 4 + r) * 128 + ((c << 4) | nl)] = f2h_bits(eluf(acc[c][r] + bv));
    }
  }
}

// ---------------------------------------------------------------------------
// fusedC: per 64-row block:
//   ff   = elu(elu(hv@w0+b0)@mf_w1+b1)                 (tile)
//   acc2 = ff@s2w0lo                                    (tile consumed)
//   h2   = agg2@g2_rel + g2b + h@g2_root                (tile)
//   t    = elu(acc2 + h2@s2w0hi + s2b0)                 (tile)
//   t    = elu(t@s2w1 + s2b1)                           (tile)
//   out  = t@s2_w2 + s2b2                               (global fp32)
// ---------------------------------------------------------------------------
__global__ __launch_bounds__(256) void fusedC(
    const u16* __restrict__ G,           // agg2
    const u16* __restrict__ A,           // h
    const u16* __restrict__ wT,
    const float* __restrict__ hv, const float* __restrict__ mf_w0,
    const float* __restrict__ mf_b0, const float* __restrict__ mf_b1,
    const float* __restrict__ g2b, const float* __restrict__ s2b0,
    const float* __restrict__ s2b1, const float* __restrict__ s2w2,
    const float* __restrict__ s2b2, float* __restrict__ out)
{
  __shared__ __align__(16) short wbuf[16384];
  __shared__ __align__(16) short tile[64 * 136];
  __shared__ float hvs[448];
  __shared__ float w0s[896];
  __shared__ float b0s[128];
  int tid = threadIdx.x;
  int wv = tid >> 6, lane = tid & 63, nl = lane & 15, q = lane >> 4;
  long blk0 = (long)blockIdx.x * 64;
  long r0 = blk0 + wv * 16;
  bool active = r0 < NROWS;
  long arow = r0 + nl;
  short* mytile = &tile[(wv * 16) * 136];

  // stage hv/w0/b0 + mf_w1 concurrently
  load_w_swz(wT + 0 * 16384, wbuf, tid);                       // mf_w1
  for (int i = tid; i < 448; i += 256) {
    long g = blk0 * 7 + i;
    hvs[i] = (g < (long)NROWS * 7) ? hv[g] : 0.0f;
  }
  for (int i = tid; i < 896; i += 256) w0s[i] = mf_w0[i];
  if (tid < 128) b0s[tid] = mf_b0[tid];
  __syncthreads();

  // lin0: 64x128 into tile (block-wide)
  for (int idx = tid; idx < 8192; idx += 256) {
    int n = idx >> 7, c = idx & 127;
    float s = b0s[c];
#pragma unroll
    for (int k = 0; k < 7; ++k) s += hvs[n * 7 + k] * w0s[k * 128 + c];
    tile[n * 136 + c] = (short)f2h_bits(eluf(s));
  }
  __syncthreads();

  f32x4 acc1[8], acc2[8];
  // ff = elu(lin0 @ mf_w1 + b1) -> tile (own rows)
  zero_acc(acc1);
  gemm_tile(acc1, mytile, wbuf, nl, q);
  epi_tile<true>(acc1, mf_b1, mytile, nl, q);
  __syncthreads();
  load_w_swz(wT + 8 * 16384, wbuf, tid); __syncthreads();      // s2w0lo
  zero_acc(acc2);
  gemm_tile(acc2, mytile, wbuf, nl, q);                        // ff @ w0lo
  __syncthreads();
  load_w_swz(wT + 6 * 16384, wbuf, tid); __syncthreads();      // g2_rel
  zero_acc(acc1);
  gemm_global(acc1, G, arow, active, wbuf, nl, q);             // agg2 @ rel
  __syncthreads();
  load_w_swz(wT + 7 * 16384, wbuf, tid); __syncthreads();      // g2_root
  gemm_global(acc1, A, arow, active, wbuf, nl, q);             // + h @ root
  epi_tile<false>(acc1, g2b, mytile, nl, q);                   // tile = h2
  __syncthreads();
  load_w_swz(wT + 9 * 16384, wbuf, tid); __syncthreads();      // s2w0hi
  gemm_tile(acc2, mytile, wbuf, nl, q);                        // + h2 @ w0hi
  epi_tile<true>(acc2, s2b0, mytile, nl, q);                   // tile = s2_0 out
  __syncthreads();
  load_w_swz(wT + 10 * 16384, wbuf, tid); __syncthreads();     // s2_w1
  zero_acc(acc1);
  gemm_tile(acc1, mytile, wbuf, nl, q);
  epi_tile<true>(acc1, s2b1, mytile, nl, q);                   // tile = s2_1 out
  __syncthreads();
  // stage w2 (256 fp32) + b2 into wbuf-as-float
  float* w2s = (float*)wbuf;
  if (tid < 256) w2s[tid] = s2w2[tid];
  if (tid < 2)   w2s[256 + tid] = s2b2[tid];
  __syncthreads();
  // final: 4 lanes per row
  int row = lane >> 2, qq = lane & 3;
  const short* xr = &mytile[row * 136 + qq * 32];
  float p0 = 0.f, p1 = 0.f;
#pragma unroll
  for (int i = 0; i < 4; ++i) {
    short8 v = *reinterpret_cast<const short8*>(xr + i * 8);
#pragma unroll
    for (int j = 0; j < 8; ++j) {
      float f = h2f((u16)v[j]);
      int cidx = qq * 32 + i * 8 + j;
      p0 += f * w2s[cidx * 2];
      p1 += f * w2s[cidx * 2 + 1];
    }
  }
  p0 += __shfl_xor(p0, 1); p0 += __shfl_xor(p0, 2);
  p1 += __shfl_xor(p1, 1); p1 += __shfl_xor(p1, 2);
  if (qq == 0 && active) {
    out[(r0 + row) * 2]     = p0 + w2s[256];
    out[(r0 + row) * 2 + 1] = p1 + w2s[257];
  }
}

// ---------------------------------------------------------------------------
// Standalone layer + mlp_face + final (fallback path).
// ---------------------------------------------------------------------------
template<bool DUAL, bool ACT>
__global__ __launch_bounds__(256) void layer_kernel(
    const u16* X, const u16* X2,
    const u16* __restrict__ W1t, const u16* __restrict__ W2t,
    const float* __restrict__ bias, u16* Y)
{
  __shared__ __align__(16) short w1s[16384];
  __shared__ __align__(16) short w2s[DUAL ? 16384 : 8];
  int tid = threadIdx.x;
  load_w_swz(W1t, w1s, tid);
  if constexpr (DUAL) load_w_swz(W2t, w2s, tid);
  __syncthreads();
  int wv = tid >> 6, lane = tid & 63, nl = lane & 15, q = lane >> 4;
  long r0 = (long)blockIdx.x * 64 + wv * 16;
  if (r0 >= NROWS) return;
  long arow = r0 + nl;
  f32x4 acc[8];
  zero_acc(acc);
  gemm_global(acc, X, arow, true, w1s, nl, q);
  if constexpr (DUAL) gemm_global(acc, X2, arow, true, w2s, nl, q);
#pragma unroll
  for (int c = 0; c < 8; ++c) {
    float bv = bias[(c << 4) | nl];
#pragma unroll
    for (int r = 0; r < 4; ++r) {
      float o = acc[c][r] + bv;
      if constexpr (ACT) o = eluf(o);
      Y[(r0 + q * 4 + r) * 128 + ((c << 4) | nl)] = f2h_bits(o);
    }
  }
}

__global__ __launch_bounds__(256) void mlp_face_kernel(
    const float* __restrict__ hv, const float* __restrict__ w0,
    const float* __restrict__ b0, const u16* __restrict__ w1t,
    const float* __restrict__ b1, u16* ff)
{
  __shared__ __align__(16) short w1s[16384];
  __shared__ __align__(16) short act0[64 * 136];
  __shared__ float hvs[448];
  __shared__ float w0s[896];
  __shared__ float b0s[128];
  int tid = threadIdx.x;
  load_w_swz(w1t, w1s, tid);
  long base = (long)blockIdx.x * 64;
  for (int i = tid; i < 448; i += 256) {
    long g = base * 7 + i;
    hvs[i] = (g < (long)NROWS * 7) ? hv[g] : 0.0f;
  }
  for (int i = tid; i < 896; i += 256) w0s[i] = w0[i];
  if (tid < 128) b0s[tid] = b0[tid];
  __syncthreads();
  for (int idx = tid; idx < 8192; idx += 256) {
    int n = idx >> 7, c = idx & 127;
    float s = b0s[c];
#pragma unroll
    for (int k = 0; k < 7; ++k) s += hvs[n * 7 + k] * w0s[k * 128 + c];
    act0[n * 136 + c] = (short)f2h_bits(eluf(s));
  }
  __syncthreads();
  int wv = tid >> 6, lane = tid & 63, nl = lane & 15, q = lane >> 4;
  long r0 = base + wv * 16;
  if (r0 >= NROWS) return;
  f32x4 acc[8];
  zero_acc(acc);
  gemm_tile(acc, &act0[(wv * 16) * 136], w1s, nl, q);
#pragma unroll
  for (int c = 0; c < 8; ++c) {
    float bv = b1[(c << 4) | nl];
#pragma unroll
    for (int r = 0; r < 4; ++r)
      ff[(r0 + q * 4 + r) * 128 + ((c << 4) | nl)] = f2h_bits(eluf(acc[c][r] + bv));
  }
}

__global__ __launch_bounds__(256) void final_kernel(
    const u16* __restrict__ x, const float* __restrict__ w2,
    const float* __restrict__ b2, float* __restrict__ out)
{
  __shared__ float w2s[256];
  __shared__ float b2s[2];
  int tid = threadIdx.x;
  w2s[tid] = w2[tid];
  if (tid < 2) b2s[tid] = b2[tid];
  __syncthreads();
  long node = (long)blockIdx.x * 64 + (tid >> 2);
  int q = tid & 3;
  if (node >= NROWS) return;
  const u16* xr = x + node * 128 + q * 32;
  float p0 = 0.f, p1 = 0.f;
#pragma unroll
  for (int i = 0; i < 4; ++i) {
    short8 v = *reinterpret_cast<const short8*>(xr + i * 8);
#pragma unroll
    for (int j = 0; j < 8; ++j) {
      float f = h2f((u16)v[j]);
      int cidx = q * 32 + i * 8 + j;
      p0 += f * w2s[cidx * 2];
      p1 += f * w2s[cidx * 2 + 1];
    }
  }
  p0 += __shfl_xor(p0, 1); p0 += __shfl_xor(p0, 2);
  p1 += __shfl_xor(p1, 1); p1 += __shfl_xor(p1, 2);
  if (q == 0) {
    out[node * 2]     = p0 + b2s[0];
    out[node * 2 + 1] = p1 + b2s[1];
  }
}

// ---------------------------------------------------------------------------
extern "C" void kernel_launch(void* const* d_in, const int* in_sizes, int n_in,
                              void* d_out, int out_size, void* d_ws, size_t ws_size,
                              hipStream_t stream) {
  const float* hv        = (const float*)d_in[0];
  const int*   ei        = (const int*)d_in[1];
  const float* mf_w0     = (const float*)d_in[2];
  const float* mf_b0     = (const float*)d_in[3];
  const float* mf_w1     = (const float*)d_in[4];
  const float* mf_b1     = (const float*)d_in[5];
  const float* g1_rel_w  = (const float*)d_in[6];
  const float* g1_rel_b  = (const float*)d_in[7];
  const float* g1_root_w = (const float*)d_in[8];
  const float* g2_rel_w  = (const float*)d_in[9];
  const float* g2_rel_b  = (const float*)d_in[10];
  const float* g2_root_w = (const float*)d_in[11];
  const float* s1_w0     = (const float*)d_in[12];
  const float* s1_b0     = (const float*)d_in[13];
  const float* s1_w1     = (const float*)d_in[14];
  const float* s1_b1     = (const float*)d_in[15];
  const float* s1_w2     = (const float*)d_in[16];
  const float* s1_b2     = (const float*)d_in[17];
  const float* s2_w0     = (const float*)d_in[18];
  const float* s2_b0     = (const float*)d_in[19];
  const float* s2_w1     = (const float*)d_in[20];
  const float* s2_b1     = (const float*)d_in[21];
  const float* s2_w2     = (const float*)d_in[22];
  const float* s2_b2     = (const float*)d_in[23];

  constexpr size_t ACT_BYTES = (size_t)NROWS * 128 * 2;     // 128e6
  constexpr size_t ADJ_BYTES = (size_t)NEDGE * 4;           // 12e6
  constexpr size_t WT_BYTES  = 11 * 16384 * 2;              // 360,448
  constexpr size_t CSR_NEED  = 2 * ACT_BYTES + ADJ_BYTES + WT_BYTES + 4096;

  char* ws = (char*)d_ws;
  u16* A   = (u16*)ws;
  u16* G   = (u16*)(ws + ACT_BYTES);
  int* adj = (int*)(ws + 2 * ACT_BYTES);
  const bool CSRP = ws_size >= CSR_NEED;                    // 268,364,544

  u16* wT;
  int* bsum;
  int* cur;
  if (CSRP) {
    wT   = (u16*)(ws + 2 * ACT_BYTES + ADJ_BYTES);          // ws tail slack
    bsum = (int*)(ws + 2 * ACT_BYTES + ADJ_BYTES + WT_BYTES);
    cur  = (int*)d_out;   // 2e6 B; consumed by gather2 before d_out written
  } else {
    // fallback: stash in d_out (final_kernel reads only d_in; writes last)
    wT   = (u16*)d_out;
    bsum = (int*)((char*)d_out + WT_BYTES);
    cur  = nullptr;
  }

  u16* mf_w1T   = wT + 0 * 16384;
  u16* g1_relT  = wT + 1 * 16384;
  u16* g1_rootT = wT + 2 * 16384;
  u16* s1_w0T   = wT + 3 * 16384;
  u16* s1_w1T   = wT + 4 * 16384;
  u16* s1_w2T   = wT + 5 * 16384;
  u16* g2_relT  = wT + 6 * 16384;
  u16* g2_rootT = wT + 7 * 16384;
  u16* s2w0loT  = wT + 8 * 16384;
  u16* s2w0hiT  = wT + 9 * 16384;
  u16* s2_w1T   = wT + 10 * 16384;

  transpose_w<<<dim3(8, 11), 256, 0, stream>>>(
      mf_w1, g1_rel_w, g1_root_w, s1_w0, s1_w1, s1_w2,
      g2_rel_w, g2_root_w, s2_w0, s2_w1, wT);

  const int gb  = (NROWS + 63) / 64;        // 7813
  const int ge4 = (NEDGE / 4 + 255) / 256;  // 2930
  const int gn  = (NROWS + 3) / 4;          // 125000

  if (CSRP) {
    (void)hipMemsetAsync(cur, 0, (size_t)NROWS * 4, stream);
    hist_kernel<<<ge4, 256, 0, stream>>>(ei, cur);
    scanA<<<NBLK_SCAN, 256, 0, stream>>>(cur, bsum);
    scanB<<<1, 512, 0, stream>>>(bsum);
    scanC<<<NBLK_SCAN, 256, 0, stream>>>(bsum, cur);
    fill_kernel<<<ge4, 256, 0, stream>>>(ei, cur, adj);     // cur -> end offs

    mlp_face_kernel<<<gb, 256, 0, stream>>>(hv, mf_w0, mf_b0, mf_w1T, mf_b1, A); // A=ff
    gather_agg<<<gn, 256, 0, stream>>>(A, cur, adj, G);                           // G=agg1
    fusedB<<<gb, 256, 0, stream>>>(G, A, wT, g1_rel_b, s1_b0, s1_b1, s1_b2);      // A=h
    gather_agg<<<gn, 256, 0, stream>>>(A, cur, adj, G);                           // G=agg2
    fusedC<<<gb, 256, 0, stream>>>(G, A, wT, hv, mf_w0, mf_b0, mf_b1,
                                   g2_rel_b, s2_b0, s2_b1, s2_w2, s2_b2,
                                   (float*)d_out);
  } else {
    mlp_face_kernel<<<gb, 256, 0, stream>>>(hv, mf_w0, mf_b0, mf_w1T, mf_b1, A);
    (void)hipMemsetAsync(G, 0, ACT_BYTES, stream);
    scatter_kernel<<<4096, 256, 0, stream>>>(A, ei, (__half2*)G);
    layer_kernel<true,  true ><<<gb, 256, 0, stream>>>(G, A, g1_relT, g1_rootT, g1_rel_b, A);
    layer_kernel<false, true ><<<gb, 256, 0, stream>>>(A, nullptr, s1_w0T, nullptr, s1_b0, A);
    layer_kernel<false, true ><<<gb, 256, 0, stream>>>(A, nullptr, s1_w1T, nullptr, s1_b1, A);
    layer_kernel<false, true ><<<gb, 256, 0, stream>>>(A, nullptr, s1_w2T, nullptr, s1_b2, A);
    (void)hipMemsetAsync(G, 0, ACT_BYTES, stream);
    scatter_kernel<<<4096, 256, 0, stream>>>(A, ei, (__half2*)G);
    layer_kernel<true,  false><<<gb, 256, 0, stream>>>(G, A, g2_relT, g2_rootT, g2_rel_b, A);
    mlp_face_kernel<<<gb, 256, 0, stream>>>(hv, mf_w0, mf_b0, mf_w1T, mf_b1, G);
    layer_kernel<true,  true ><<<gb, 256, 0, stream>>>(G, A, s2w0loT, s2w0hiT, s2_b0, G);
    layer_kernel<false, true ><<<gb, 256, 0, stream>>>(G, nullptr, s2_w1T, nullptr, s2_b1, G);
    final_kernel<<<gb, 256, 0, stream>>>(G, s2_w2, s2_b2, (float*)d_out);
  }
}

// Round 9
// 1757.931 us; speedup vs baseline: 1.2719x; 1.2719x over previous
//
#include <hip/hip_runtime.h>
#include <hip/hip_bf16.h>
#include <hip/hip_fp16.h>
#include <type_traits>
#include <utility>

// FaceModel: N=500000 nodes, E=3000000 edges, F=128. fp32 in/out, f16 internal.
// R9: revert R8's barrier-heavy fusion (833us fusedC @ 11.7% occupancy).
// Back to R7 topology + PERSISTENT CHUNK LOOPS: grid <= resident capacity,
// weights staged into LDS once per block, then barrier-free streaming over
// 64-row chunks. Keeps R8's x4-batched hist/fill (ILP on atomics).
// Layout: ws = A(128e6) + G(128e6) + adj(12e6) + wT/bsum slack; cur in d_out
// (fully consumed by gather2 before final writes d_out).

#define NROWS 500000
#define NEDGE 3000000
#define NCHUNK ((NROWS + 63) / 64)          // 7813
#define SCAN_CHUNK 1024
#define NBLK_SCAN ((NROWS + SCAN_CHUNK - 1) / SCAN_CHUNK)   // 489

typedef unsigned short u16;
using short8 = __attribute__((ext_vector_type(8))) short;
using half8  = __attribute__((ext_vector_type(8))) _Float16;
using f32x4  = __attribute__((ext_vector_type(4))) float;

__device__ __forceinline__ u16 f2h_bits(float f) {
  _Float16 h = (_Float16)f;
  return __builtin_bit_cast(u16, h);
}
__device__ __forceinline__ float h2f(u16 b) {
  return (float)__builtin_bit_cast(_Float16, b);
}
__device__ __forceinline__ float eluf(float x) { return x > 0.0f ? x : expm1f(x); }

// --- f16 packed atomic add with fallback (scatter fallback path only) ------
template <typename T, typename = void> struct HasUnsafeAdd : std::false_type {};
template <typename T>
struct HasUnsafeAdd<T, std::void_t<decltype(unsafeAtomicAdd(
    std::declval<T*>(), std::declval<T>()))>> : std::true_type {};
template <bool HAS> struct AtomAdd;
template <> struct AtomAdd<true> {
  template <class T> __device__ static void go(T* p, T v) { unsafeAtomicAdd(p, v); }
};
template <> struct AtomAdd<false> {
  template <class T> __device__ static void go(T* p, T v) {
    unsigned* up = reinterpret_cast<unsigned*>(p);
    unsigned old = *up;
    while (true) {
      unsigned assumed = old;
      T cur = __builtin_bit_cast(T, assumed);
      T nw = __hadd2(cur, v);
      old = atomicCAS(up, assumed, __builtin_bit_cast(unsigned, nw));
      if (old == assumed) break;
    }
  }
};
__device__ __forceinline__ void atomAddH2(__half2* p, __half2 v) {
  AtomAdd<HasUnsafeAdd<__half2>::value>::go(p, v);
}

// ---------------------------------------------------------------------------
// Weight transpose fp32 -> f16 stash: out[slot][n*128+k] = W[k][n].
// Slots: 0 mf_w1, 1 g1_rel, 2 g1_root, 3 s1_w0, 4 s1_w1, 5 s1_w2,
//        6 g2_rel, 7 g2_root, 8 s2_w0[0:128], 9 s2_w0[128:256], 10 s2_w1
// ---------------------------------------------------------------------------
__global__ __launch_bounds__(256) void transpose_w(
    const float* p0, const float* p1, const float* p2, const float* p3,
    const float* p4, const float* p5, const float* p6, const float* p7,
    const float* p8, const float* p10, u16* dst)
{
  const float* src = p0; int eoff = 0;
  switch (blockIdx.y) {
    case 1: src = p1; break;  case 2: src = p2; break;
    case 3: src = p3; break;  case 4: src = p4; break;
    case 5: src = p5; break;  case 6: src = p6; break;
    case 7: src = p7; break;  case 8: src = p8; break;
    case 9: src = p8; eoff = 16384; break;
    case 10: src = p10; break;
    default: break;
  }
  u16* out = dst + (size_t)blockIdx.y * 16384;
  for (int i = threadIdx.x + blockIdx.x * 256; i < 16384; i += 2048) {
    int n = i >> 7, k = i & 127;
    out[i] = f2h_bits(src[eoff + k * 128 + n]);
  }
}

// ---------------------------------------------------------------------------
// CSR build (x4-batched). cur: counts -> start offsets -> end offsets.
// ---------------------------------------------------------------------------
__global__ __launch_bounds__(256) void hist_kernel(const int* __restrict__ ei,
                                                   int* __restrict__ cur) {
  int base = (blockIdx.x * 256 + threadIdx.x) * 4;
  if (base >= NEDGE) return;
  int4 d4 = *reinterpret_cast<const int4*>(ei + NEDGE + base);
  atomicAdd(&cur[d4.x], 1);
  atomicAdd(&cur[d4.y], 1);
  atomicAdd(&cur[d4.z], 1);
  atomicAdd(&cur[d4.w], 1);
}

__global__ __launch_bounds__(256) void scanA(const int* __restrict__ cur,
                                             int* __restrict__ bsum) {
  __shared__ int sdata[256];
  int b = blockIdx.x, tid = threadIdx.x;
  int base = b * SCAN_CHUNK + tid * 4;
  int s = 0;
#pragma unroll
  for (int t = 0; t < 4; ++t) {
    int i = base + t;
    if (i < NROWS) s += cur[i];
  }
  sdata[tid] = s;
  __syncthreads();
  for (int off = 128; off > 0; off >>= 1) {
    if (tid < off) sdata[tid] += sdata[tid + off];
    __syncthreads();
  }
  if (tid == 0) bsum[b] = sdata[0];
}

__global__ __launch_bounds__(512) void scanB(int* bsum) {   // in-place -> excl
  __shared__ int sdata[512];
  int tid = threadIdx.x;
  int v = (tid < NBLK_SCAN) ? bsum[tid] : 0;
  sdata[tid] = v;
  __syncthreads();
  for (int off = 1; off < 512; off <<= 1) {
    int val = (tid >= off) ? sdata[tid - off] : 0;
    __syncthreads();
    sdata[tid] += val;
    __syncthreads();
  }
  if (tid < NBLK_SCAN) bsum[tid] = sdata[tid] - v;
}

__global__ __launch_bounds__(256) void scanC(const int* __restrict__ boff,
                                             int* __restrict__ cur) {
  __shared__ int sdata[256];
  int b = blockIdx.x, tid = threadIdx.x;
  int base = b * SCAN_CHUNK + tid * 4;
  int v[4]; int s = 0;
#pragma unroll
  for (int t = 0; t < 4; ++t) {
    int i = base + t;
    v[t] = (i < NROWS) ? cur[i] : 0;
    s += v[t];
  }
  sdata[tid] = s;
  __syncthreads();
  for (int off = 1; off < 256; off <<= 1) {
    int val = (tid >= off) ? sdata[tid - off] : 0;
    __syncthreads();
    sdata[tid] += val;
    __syncthreads();
  }
  int excl = sdata[tid] - s + boff[b];
#pragma unroll
  for (int t = 0; t < 4; ++t) {
    int i = base + t;
    if (i < NROWS) cur[i] = excl;
    excl += v[t];
  }
}

__global__ __launch_bounds__(256) void fill_kernel(const int* __restrict__ ei,
                                                   int* __restrict__ cur,
                                                   int* __restrict__ adj) {
  int base = (blockIdx.x * 256 + threadIdx.x) * 4;
  if (base >= NEDGE) return;
  int4 d4 = *reinterpret_cast<const int4*>(ei + NEDGE + base);
  int4 s4 = *reinterpret_cast<const int4*>(ei + base);
  int p0 = atomicAdd(&cur[d4.x], 1);
  int p1 = atomicAdd(&cur[d4.y], 1);
  int p2 = atomicAdd(&cur[d4.z], 1);
  int p3 = atomicAdd(&cur[d4.w], 1);
  adj[p0] = s4.x; adj[p1] = s4.y; adj[p2] = s4.z; adj[p3] = s4.w;
}

// ---------------------------------------------------------------------------
// Gather segment-sum: wave per node, 8 rows batched, fp32 accumulate.
// ---------------------------------------------------------------------------
__global__ __launch_bounds__(256) void gather_agg(
    const u16* __restrict__ x, const int* __restrict__ cend,
    const int* __restrict__ adj, u16* __restrict__ agg)
{
  int wv = threadIdx.x >> 6, lane = threadIdx.x & 63;
  long node = (long)blockIdx.x * 4 + wv;
  if (node >= NROWS) return;
  int beg = (node == 0) ? 0 : cend[node - 1];
  int end = cend[node];
  float a0 = 0.f, a1 = 0.f;
  for (int j = beg; j < end; j += 8) {
    int take = end - j;
    if (take > 8) take = 8;
    int srcv = (lane < take) ? adj[j + lane] : 0;
    unsigned hb[8];
#pragma unroll
    for (int t = 0; t < 8; ++t) {
      if (t < take) {
        int src = __shfl(srcv, t);
        hb[t] = *reinterpret_cast<const unsigned*>(x + (long)src * 128 + lane * 2);
      }
    }
#pragma unroll
    for (int t = 0; t < 8; ++t) {
      if (t < take) {
        __half2 h = __builtin_bit_cast(__half2, hb[t]);
        a0 += (float)h.x;
        a1 += (float)h.y;
      }
    }
  }
  __half2 r;
  r.x = __float2half(a0);
  r.y = __float2half(a1);
  *reinterpret_cast<__half2*>(agg + node * 128 + lane * 2) = r;
}

// ---------------------------------------------------------------------------
// Atomic scatter (fallback path only).
// ---------------------------------------------------------------------------
__global__ __launch_bounds__(256) void scatter_kernel(
    const u16* __restrict__ x, const int* __restrict__ ei,
    __half2* __restrict__ agg)
{
  int gtid = blockIdx.x * 256 + threadIdx.x;
  int wid = gtid >> 6, lane = gtid & 63;
  int nw = gridDim.x * 4;
  for (int e = wid; e < NEDGE; e += nw) {
    int s = ei[e];
    int d = ei[NEDGE + e];
    __half2 h = *reinterpret_cast<const __half2*>(x + (long)s * 128 + lane * 2);
    atomAddH2(agg + (long)d * 64 + lane, h);
  }
}

// ---------------------------------------------------------------------------
// MFMA helpers.
// ---------------------------------------------------------------------------
__device__ __forceinline__ void load_w_swz(const u16* Wt, short* ws, int tid) {
  for (int c = tid; c < 2048; c += 256) {
    int n = c >> 4, kb = c & 15;
    short8 v = *reinterpret_cast<const short8*>(Wt + n * 128 + kb * 8);
    *reinterpret_cast<short8*>(ws + ((n << 4) | (kb ^ (n & 15))) * 8) = v;
  }
}
__device__ __forceinline__ half8 read_b_swz(const short* ws, int col, int kb) {
  short8 v = *reinterpret_cast<const short8*>(ws + ((col << 4) | (kb ^ (col & 15))) * 8);
  return __builtin_bit_cast(half8, v);
}
__device__ __forceinline__ void gemm_global(f32x4* acc, const u16* X, long arow,
                                            bool active, const short* wbuf,
                                            int nl, int q) {
#pragma unroll
  for (int s = 0; s < 4; ++s) {
    int kofs = s * 32 + q * 8, kb = (s << 2) | q;
    half8 a = half8{0,0,0,0,0,0,0,0};
    if (active)
      a = __builtin_bit_cast(half8,
          *reinterpret_cast<const short8*>(X + arow * 128 + kofs));
#pragma unroll
    for (int c = 0; c < 8; ++c) {
      half8 b = read_b_swz(wbuf, (c << 4) | nl, kb);
      acc[c] = __builtin_amdgcn_mfma_f32_16x16x32_f16(a, b, acc[c], 0, 0, 0);
    }
  }
}
__device__ __forceinline__ void gemm_tile(f32x4* acc, const short* mytile,
                                          const short* wbuf, int nl, int q) {
#pragma unroll
  for (int s = 0; s < 4; ++s) {
    int kofs = s * 32 + q * 8, kb = (s << 2) | q;
    half8 a = __builtin_bit_cast(half8,
        *reinterpret_cast<const short8*>(&mytile[nl * 136 + kofs]));
#pragma unroll
    for (int c = 0; c < 8; ++c) {
      half8 b = read_b_swz(wbuf, (c << 4) | nl, kb);
      acc[c] = __builtin_amdgcn_mfma_f32_16x16x32_f16(a, b, acc[c], 0, 0, 0);
    }
  }
}
__device__ __forceinline__ void zero_acc(f32x4* acc) {
#pragma unroll
  for (int c = 0; c < 8; ++c) acc[c] = f32x4{0.f, 0.f, 0.f, 0.f};
}

// ---------------------------------------------------------------------------
// Persistent layer: weights staged ONCE per block, then barrier-free loop
// over 64-row chunks (chunk = blockIdx + k*gridDim). In-place safe.
// ---------------------------------------------------------------------------
template<bool DUAL, bool ACT>
__global__ __launch_bounds__(256) void layer_kernel(
    const u16* X, const u16* X2,
    const u16* __restrict__ W1t, const u16* __restrict__ W2t,
    const float* __restrict__ bias, u16* Y)
{
  __shared__ __align__(16) short w1s[16384];
  __shared__ __align__(16) short w2s[DUAL ? 16384 : 8];
  __shared__ float bs[128];
  int tid = threadIdx.x;
  load_w_swz(W1t, w1s, tid);
  if constexpr (DUAL) load_w_swz(W2t, w2s, tid);
  if (tid < 128) bs[tid] = bias[tid];
  __syncthreads();

  int wv = tid >> 6, lane = tid & 63, nl = lane & 15, q = lane >> 4;
  for (int ch = blockIdx.x; ch < NCHUNK; ch += gridDim.x) {
    long r0 = (long)ch * 64 + wv * 16;
    if (r0 >= NROWS) continue;
    long arow = r0 + nl;
    f32x4 acc[8];
    zero_acc(acc);
    gemm_global(acc, X, arow, true, w1s, nl, q);
    if constexpr (DUAL) gemm_global(acc, X2, arow, true, w2s, nl, q);
#pragma unroll
    for (int c = 0; c < 8; ++c) {
      float bv = bs[(c << 4) | nl];
#pragma unroll
      for (int r = 0; r < 4; ++r) {
        float o = acc[c][r] + bv;
        if constexpr (ACT) o = eluf(o);
        Y[(r0 + q * 4 + r) * 128 + ((c << 4) | nl)] = f2h_bits(o);
      }
    }
  }
}

// ---------------------------------------------------------------------------
// Persistent mlp_face: w1 staged once; per chunk: hv stage + lin0 (VALU) into
// block tile + MFMA. 3 barriers per chunk (tile is block-shared).
// ---------------------------------------------------------------------------
__global__ __launch_bounds__(256) void mlp_face_kernel(
    const float* __restrict__ hv, const float* __restrict__ w0,
    const float* __restrict__ b0, const u16* __restrict__ w1t,
    const float* __restrict__ b1, u16* ff)
{
  __shared__ __align__(16) short w1s[16384];
  __shared__ __align__(16) short act0[64 * 136];
  __shared__ float hvs[448];
  __shared__ float w0s[896];
  __shared__ float b0s[128];
  __shared__ float b1s[128];
  int tid = threadIdx.x;
  load_w_swz(w1t, w1s, tid);
  for (int i = tid; i < 896; i += 256) w0s[i] = w0[i];
  if (tid < 128) { b0s[tid] = b0[tid]; b1s[tid] = b1[tid]; }
  int wv = tid >> 6, lane = tid & 63, nl = lane & 15, q = lane >> 4;

  for (int ch = blockIdx.x; ch < NCHUNK; ch += gridDim.x) {
    long base = (long)ch * 64;
    __syncthreads();                       // protect hvs/act0 reuse
    for (int i = tid; i < 448; i += 256) {
      long g = base * 7 + i;
      hvs[i] = (g < (long)NROWS * 7) ? hv[g] : 0.0f;
    }
    __syncthreads();
    for (int idx = tid; idx < 8192; idx += 256) {
      int n = idx >> 7, c = idx & 127;
      float s = b0s[c];
#pragma unroll
      for (int k = 0; k < 7; ++k) s += hvs[n * 7 + k] * w0s[k * 128 + c];
      act0[n * 136 + c] = (short)f2h_bits(eluf(s));
    }
    __syncthreads();
    long r0 = base + wv * 16;
    if (r0 >= NROWS) continue;
    f32x4 acc[8];
    zero_acc(acc);
    gemm_tile(acc, &act0[(wv * 16) * 136], w1s, nl, q);
#pragma unroll
    for (int c = 0; c < 8; ++c) {
      float bv = b1s[(c << 4) | nl];
#pragma unroll
      for (int r = 0; r < 4; ++r)
        ff[(r0 + q * 4 + r) * 128 + ((c << 4) | nl)] = f2h_bits(eluf(acc[c][r] + bv));
    }
  }
}

// ---------------------------------------------------------------------------
// Persistent final: out[n][j] = sum_c x[n][c]*W[c][j] + b[j], j<2.
// ---------------------------------------------------------------------------
__global__ __launch_bounds__(256) void final_kernel(
    const u16* __restrict__ x, const float* __restrict__ w2,
    const float* __restrict__ b2, float* __restrict__ out)
{
  __shared__ float w2s[256];
  __shared__ float b2s[2];
  int tid = threadIdx.x;
  w2s[tid] = w2[tid];
  if (tid < 2) b2s[tid] = b2[tid];
  __syncthreads();
  for (int ch = blockIdx.x; ch < NCHUNK; ch += gridDim.x) {
    long node = (long)ch * 64 + (tid >> 2);
    int q = tid & 3;
    if (node >= NROWS) continue;
    const u16* xr = x + node * 128 + q * 32;
    float p0 = 0.f, p1 = 0.f;
#pragma unroll
    for (int i = 0; i < 4; ++i) {
      short8 v = *reinterpret_cast<const short8*>(xr + i * 8);
#pragma unroll
      for (int j = 0; j < 8; ++j) {
        float f = h2f((u16)v[j]);
        int cidx = q * 32 + i * 8 + j;
        p0 += f * w2s[cidx * 2];
        p1 += f * w2s[cidx * 2 + 1];
      }
    }
    p0 += __shfl_xor(p0, 1); p0 += __shfl_xor(p0, 2);
    p1 += __shfl_xor(p1, 1); p1 += __shfl_xor(p1, 2);
    if (q == 0) {
      out[node * 2]     = p0 + b2s[0];
      out[node * 2 + 1] = p1 + b2s[1];
    }
  }
}

// ---------------------------------------------------------------------------
extern "C" void kernel_launch(void* const* d_in, const int* in_sizes, int n_in,
                              void* d_out, int out_size, void* d_ws, size_t ws_size,
                              hipStream_t stream) {
  const float* hv        = (const float*)d_in[0];
  const int*   ei        = (const int*)d_in[1];
  const float* mf_w0     = (const float*)d_in[2];
  const float* mf_b0     = (const float*)d_in[3];
  const float* mf_w1     = (const float*)d_in[4];
  const float* mf_b1     = (const float*)d_in[5];
  const float* g1_rel_w  = (const float*)d_in[6];
  const float* g1_rel_b  = (const float*)d_in[7];
  const float* g1_root_w = (const float*)d_in[8];
  const float* g2_rel_w  = (const float*)d_in[9];
  const float* g2_rel_b  = (const float*)d_in[10];
  const float* g2_root_w = (const float*)d_in[11];
  const float* s1_w0     = (const float*)d_in[12];
  const float* s1_b0     = (const float*)d_in[13];
  const float* s1_w1     = (const float*)d_in[14];
  const float* s1_b1     = (const float*)d_in[15];
  const float* s1_w2     = (const float*)d_in[16];
  const float* s1_b2     = (const float*)d_in[17];
  const float* s2_w0     = (const float*)d_in[18];
  const float* s2_b0     = (const float*)d_in[19];
  const float* s2_w1     = (const float*)d_in[20];
  const float* s2_b1     = (const float*)d_in[21];
  const float* s2_w2     = (const float*)d_in[22];
  const float* s2_b2     = (const float*)d_in[23];

  constexpr size_t ACT_BYTES = (size_t)NROWS * 128 * 2;     // 128e6
  constexpr size_t ADJ_BYTES = (size_t)NEDGE * 4;           // 12e6
  constexpr size_t WT_BYTES  = 11 * 16384 * 2;              // 360,448
  constexpr size_t CSR_NEED  = 2 * ACT_BYTES + ADJ_BYTES + WT_BYTES + 4096;

  char* ws = (char*)d_ws;
  u16* A   = (u16*)ws;
  u16* G   = (u16*)(ws + ACT_BYTES);
  int* adj = (int*)(ws + 2 * ACT_BYTES);
  const bool CSRP = ws_size >= CSR_NEED;                    // 268,364,544

  u16* wT;
  int* bsum;
  int* cur;
  if (CSRP) {
    wT   = (u16*)(ws + 2 * ACT_BYTES + ADJ_BYTES);
    bsum = (int*)(ws + 2 * ACT_BYTES + ADJ_BYTES + WT_BYTES);
    cur  = (int*)d_out;   // consumed by gather2 before d_out written
  } else {
    wT   = (u16*)d_out;   // fallback stash (final reads only d_in)
    bsum = (int*)((char*)d_out + WT_BYTES);
    cur  = nullptr;
  }

  u16* mf_w1T   = wT + 0 * 16384;
  u16* g1_relT  = wT + 1 * 16384;
  u16* g1_rootT = wT + 2 * 16384;
  u16* s1_w0T   = wT + 3 * 16384;
  u16* s1_w1T   = wT + 4 * 16384;
  u16* s1_w2T   = wT + 5 * 16384;
  u16* g2_relT  = wT + 6 * 16384;
  u16* g2_rootT = wT + 7 * 16384;
  u16* s2w0loT  = wT + 8 * 16384;
  u16* s2w0hiT  = wT + 9 * 16384;
  u16* s2_w1T   = wT + 10 * 16384;

  transpose_w<<<dim3(8, 11), 256, 0, stream>>>(
      mf_w1, g1_rel_w, g1_root_w, s1_w0, s1_w1, s1_w2,
      g2_rel_w, g2_root_w, s2_w0, s2_w1, wT);

  // Persistent grids (<= resident capacity; LDS-bound):
  const int gS = 768;    // single-weight layer: ~33KB LDS -> >=3 blocks/CU
  const int gD = 512;    // dual-weight layer:   ~65KB LDS -> 2 blocks/CU
  const int gM = 512;    // mlp_face:            ~56KB LDS -> 2 blocks/CU
  const int gF = 1024;   // final: ~1KB LDS
  const int ge4 = (NEDGE / 4 + 255) / 256;  // 2930
  const int gn  = (NROWS + 3) / 4;          // 125000

  if (CSRP) {
    (void)hipMemsetAsync(cur, 0, (size_t)NROWS * 4, stream);
    hist_kernel<<<ge4, 256, 0, stream>>>(ei, cur);
    scanA<<<NBLK_SCAN, 256, 0, stream>>>(cur, bsum);
    scanB<<<1, 512, 0, stream>>>(bsum);
    scanC<<<NBLK_SCAN, 256, 0, stream>>>(bsum, cur);
    fill_kernel<<<ge4, 256, 0, stream>>>(ei, cur, adj);     // cur -> end offs

    mlp_face_kernel<<<gM, 256, 0, stream>>>(hv, mf_w0, mf_b0, mf_w1T, mf_b1, A); // A=ff
    gather_agg<<<gn, 256, 0, stream>>>(A, cur, adj, G);                           // G=agg1
    layer_kernel<true,  true ><<<gD, 256, 0, stream>>>(G, A, g1_relT, g1_rootT, g1_rel_b, A); // A=h
    layer_kernel<false, true ><<<gS, 256, 0, stream>>>(A, nullptr, s1_w0T, nullptr, s1_b0, A);
    layer_kernel<false, true ><<<gS, 256, 0, stream>>>(A, nullptr, s1_w1T, nullptr, s1_b1, A);
    layer_kernel<false, true ><<<gS, 256, 0, stream>>>(A, nullptr, s1_w2T, nullptr, s1_b2, A);
    gather_agg<<<gn, 256, 0, stream>>>(A, cur, adj, G);                           // G=agg2
    layer_kernel<true,  false><<<gD, 256, 0, stream>>>(G, A, g2_relT, g2_rootT, g2_rel_b, A); // A=h2
    mlp_face_kernel<<<gM, 256, 0, stream>>>(hv, mf_w0, mf_b0, mf_w1T, mf_b1, G);  // G=ff
    layer_kernel<true,  true ><<<gD, 256, 0, stream>>>(G, A, s2w0loT, s2w0hiT, s2_b0, G);
    layer_kernel<false, true ><<<gS, 256, 0, stream>>>(G, nullptr, s2_w1T, nullptr, s2_b1, G);
    final_kernel<<<gF, 256, 0, stream>>>(G, s2_w2, s2_b2, (float*)d_out);
  } else {
    mlp_face_kernel<<<gM, 256, 0, stream>>>(hv, mf_w0, mf_b0, mf_w1T, mf_b1, A);
    (void)hipMemsetAsync(G, 0, ACT_BYTES, stream);
    scatter_kernel<<<4096, 256, 0, stream>>>(A, ei, (__half2*)G);
    layer_kernel<true,  true ><<<gD, 256, 0, stream>>>(G, A, g1_relT, g1_rootT, g1_rel_b, A);
    layer_kernel<false, true ><<<gS, 256, 0, stream>>>(A, nullptr, s1_w0T, nullptr, s1_b0, A);
    layer_kernel<false, true ><<<gS, 256, 0, stream>>>(A, nullptr, s1_w1T, nullptr, s1_b1, A);
    layer_kernel<false, true ><<<gS, 256, 0, stream>>>(A, nullptr, s1_w2T, nullptr, s1_b2, A);
    (void)hipMemsetAsync(G, 0, ACT_BYTES, stream);
    scatter_kernel<<<4096, 256, 0, stream>>>(A, ei, (__half2*)G);
    layer_kernel<true,  false><<<gD, 256, 0, stream>>>(G, A, g2_relT, g2_rootT, g2_rel_b, A);
    mlp_face_kernel<<<gM, 256, 0, stream>>>(hv, mf_w0, mf_b0, mf_w1T, mf_b1, G);
    layer_kernel<true,  true ><<<gD, 256, 0, stream>>>(G, A, s2w0loT, s2w0hiT, s2_b0, G);
    layer_kernel<false, true ><<<gS, 256, 0, stream>>>(G, nullptr, s2_w1T, nullptr, s2_b1, G);
    final_kernel<<<gF, 256, 0, stream>>>(G, s2_w2, s2_b2, (float*)d_out);
  }
}

// Round 10
// 1743.766 us; speedup vs baseline: 1.2823x; 1.0081x over previous
//
#include <hip/hip_runtime.h>
#include <hip/hip_bf16.h>
#include <hip/hip_fp16.h>
#include <type_traits>
#include <utility>

// FaceModel: N=500000 nodes, E=3000000 edges, F=128. fp32 in/out, f16 internal.
// R10: fill_kernel adj writes -> atomicExch. Plain 4B stores at random
// positions full-line-amplify through per-XCD private L2s (measured 196MB
// WRITE for a 12MB array); device-scope atomics execute memory-side (shared
// point of coherence) so lines accumulate all ~16 entries before one
// eviction. Also: single-weight persistent layers 768->1024 blocks (4/CU).
// Everything else identical to R9 (1758us).

#define NROWS 500000
#define NEDGE 3000000
#define NCHUNK ((NROWS + 63) / 64)          // 7813
#define SCAN_CHUNK 1024
#define NBLK_SCAN ((NROWS + SCAN_CHUNK - 1) / SCAN_CHUNK)   // 489

typedef unsigned short u16;
using short8 = __attribute__((ext_vector_type(8))) short;
using half8  = __attribute__((ext_vector_type(8))) _Float16;
using f32x4  = __attribute__((ext_vector_type(4))) float;

__device__ __forceinline__ u16 f2h_bits(float f) {
  _Float16 h = (_Float16)f;
  return __builtin_bit_cast(u16, h);
}
__device__ __forceinline__ float h2f(u16 b) {
  return (float)__builtin_bit_cast(_Float16, b);
}
__device__ __forceinline__ float eluf(float x) { return x > 0.0f ? x : expm1f(x); }

// --- f16 packed atomic add with fallback (scatter fallback path only) ------
template <typename T, typename = void> struct HasUnsafeAdd : std::false_type {};
template <typename T>
struct HasUnsafeAdd<T, std::void_t<decltype(unsafeAtomicAdd(
    std::declval<T*>(), std::declval<T>()))>> : std::true_type {};
template <bool HAS> struct AtomAdd;
template <> struct AtomAdd<true> {
  template <class T> __device__ static void go(T* p, T v) { unsafeAtomicAdd(p, v); }
};
template <> struct AtomAdd<false> {
  template <class T> __device__ static void go(T* p, T v) {
    unsigned* up = reinterpret_cast<unsigned*>(p);
    unsigned old = *up;
    while (true) {
      unsigned assumed = old;
      T cur = __builtin_bit_cast(T, assumed);
      T nw = __hadd2(cur, v);
      old = atomicCAS(up, assumed, __builtin_bit_cast(unsigned, nw));
      if (old == assumed) break;
    }
  }
};
__device__ __forceinline__ void atomAddH2(__half2* p, __half2 v) {
  AtomAdd<HasUnsafeAdd<__half2>::value>::go(p, v);
}

// ---------------------------------------------------------------------------
// Weight transpose fp32 -> f16 stash: out[slot][n*128+k] = W[k][n].
// Slots: 0 mf_w1, 1 g1_rel, 2 g1_root, 3 s1_w0, 4 s1_w1, 5 s1_w2,
//        6 g2_rel, 7 g2_root, 8 s2_w0[0:128], 9 s2_w0[128:256], 10 s2_w1
// ---------------------------------------------------------------------------
__global__ __launch_bounds__(256) void transpose_w(
    const float* p0, const float* p1, const float* p2, const float* p3,
    const float* p4, const float* p5, const float* p6, const float* p7,
    const float* p8, const float* p10, u16* dst)
{
  const float* src = p0; int eoff = 0;
  switch (blockIdx.y) {
    case 1: src = p1; break;  case 2: src = p2; break;
    case 3: src = p3; break;  case 4: src = p4; break;
    case 5: src = p5; break;  case 6: src = p6; break;
    case 7: src = p7; break;  case 8: src = p8; break;
    case 9: src = p8; eoff = 16384; break;
    case 10: src = p10; break;
    default: break;
  }
  u16* out = dst + (size_t)blockIdx.y * 16384;
  for (int i = threadIdx.x + blockIdx.x * 256; i < 16384; i += 2048) {
    int n = i >> 7, k = i & 127;
    out[i] = f2h_bits(src[eoff + k * 128 + n]);
  }
}

// ---------------------------------------------------------------------------
// CSR build (x4-batched). cur: counts -> start offsets -> end offsets.
// ---------------------------------------------------------------------------
__global__ __launch_bounds__(256) void hist_kernel(const int* __restrict__ ei,
                                                   int* __restrict__ cur) {
  int base = (blockIdx.x * 256 + threadIdx.x) * 4;
  if (base >= NEDGE) return;
  int4 d4 = *reinterpret_cast<const int4*>(ei + NEDGE + base);
  atomicAdd(&cur[d4.x], 1);
  atomicAdd(&cur[d4.y], 1);
  atomicAdd(&cur[d4.z], 1);
  atomicAdd(&cur[d4.w], 1);
}

__global__ __launch_bounds__(256) void scanA(const int* __restrict__ cur,
                                             int* __restrict__ bsum) {
  __shared__ int sdata[256];
  int b = blockIdx.x, tid = threadIdx.x;
  int base = b * SCAN_CHUNK + tid * 4;
  int s = 0;
#pragma unroll
  for (int t = 0; t < 4; ++t) {
    int i = base + t;
    if (i < NROWS) s += cur[i];
  }
  sdata[tid] = s;
  __syncthreads();
  for (int off = 128; off > 0; off >>= 1) {
    if (tid < off) sdata[tid] += sdata[tid + off];
    __syncthreads();
  }
  if (tid == 0) bsum[b] = sdata[0];
}

__global__ __launch_bounds__(512) void scanB(int* bsum) {   // in-place -> excl
  __shared__ int sdata[512];
  int tid = threadIdx.x;
  int v = (tid < NBLK_SCAN) ? bsum[tid] : 0;
  sdata[tid] = v;
  __syncthreads();
  for (int off = 1; off < 512; off <<= 1) {
    int val = (tid >= off) ? sdata[tid - off] : 0;
    __syncthreads();
    sdata[tid] += val;
    __syncthreads();
  }
  if (tid < NBLK_SCAN) bsum[tid] = sdata[tid] - v;
}

__global__ __launch_bounds__(256) void scanC(const int* __restrict__ boff,
                                             int* __restrict__ cur) {
  __shared__ int sdata[256];
  int b = blockIdx.x, tid = threadIdx.x;
  int base = b * SCAN_CHUNK + tid * 4;
  int v[4]; int s = 0;
#pragma unroll
  for (int t = 0; t < 4; ++t) {
    int i = base + t;
    v[t] = (i < NROWS) ? cur[i] : 0;
    s += v[t];
  }
  sdata[tid] = s;
  __syncthreads();
  for (int off = 1; off < 256; off <<= 1) {
    int val = (tid >= off) ? sdata[tid - off] : 0;
    __syncthreads();
    sdata[tid] += val;
    __syncthreads();
  }
  int excl = sdata[tid] - s + boff[b];
#pragma unroll
  for (int t = 0; t < 4; ++t) {
    int i = base + t;
    if (i < NROWS) cur[i] = excl;
    excl += v[t];
  }
}

// adj writes via atomicExch: device-scope atomics execute at the memory-side
// coherence point (not per-XCD L2) -> no 64B dirty-line amplification.
__global__ __launch_bounds__(256) void fill_kernel(const int* __restrict__ ei,
                                                   int* __restrict__ cur,
                                                   int* __restrict__ adj) {
  int base = (blockIdx.x * 256 + threadIdx.x) * 4;
  if (base >= NEDGE) return;
  int4 d4 = *reinterpret_cast<const int4*>(ei + NEDGE + base);
  int4 s4 = *reinterpret_cast<const int4*>(ei + base);
  int p0 = atomicAdd(&cur[d4.x], 1);
  int p1 = atomicAdd(&cur[d4.y], 1);
  int p2 = atomicAdd(&cur[d4.z], 1);
  int p3 = atomicAdd(&cur[d4.w], 1);
  atomicExch(&adj[p0], s4.x);
  atomicExch(&adj[p1], s4.y);
  atomicExch(&adj[p2], s4.z);
  atomicExch(&adj[p3], s4.w);
}

// ---------------------------------------------------------------------------
// Gather segment-sum: wave per node, 8 rows batched, fp32 accumulate.
// ---------------------------------------------------------------------------
__global__ __launch_bounds__(256) void gather_agg(
    const u16* __restrict__ x, const int* __restrict__ cend,
    const int* __restrict__ adj, u16* __restrict__ agg)
{
  int wv = threadIdx.x >> 6, lane = threadIdx.x & 63;
  long node = (long)blockIdx.x * 4 + wv;
  if (node >= NROWS) return;
  int beg = (node == 0) ? 0 : cend[node - 1];
  int end = cend[node];
  float a0 = 0.f, a1 = 0.f;
  for (int j = beg; j < end; j += 8) {
    int take = end - j;
    if (take > 8) take = 8;
    int srcv = (lane < take) ? adj[j + lane] : 0;
    unsigned hb[8];
#pragma unroll
    for (int t = 0; t < 8; ++t) {
      if (t < take) {
        int src = __shfl(srcv, t);
        hb[t] = *reinterpret_cast<const unsigned*>(x + (long)src * 128 + lane * 2);
      }
    }
#pragma unroll
    for (int t = 0; t < 8; ++t) {
      if (t < take) {
        __half2 h = __builtin_bit_cast(__half2, hb[t]);
        a0 += (float)h.x;
        a1 += (float)h.y;
      }
    }
  }
  __half2 r;
  r.x = __float2half(a0);
  r.y = __float2half(a1);
  *reinterpret_cast<__half2*>(agg + node * 128 + lane * 2) = r;
}

// ---------------------------------------------------------------------------
// Atomic scatter (fallback path only).
// ---------------------------------------------------------------------------
__global__ __launch_bounds__(256) void scatter_kernel(
    const u16* __restrict__ x, const int* __restrict__ ei,
    __half2* __restrict__ agg)
{
  int gtid = blockIdx.x * 256 + threadIdx.x;
  int wid = gtid >> 6, lane = gtid & 63;
  int nw = gridDim.x * 4;
  for (int e = wid; e < NEDGE; e += nw) {
    int s = ei[e];
    int d = ei[NEDGE + e];
    __half2 h = *reinterpret_cast<const __half2*>(x + (long)s * 128 + lane * 2);
    atomAddH2(agg + (long)d * 64 + lane, h);
  }
}

// ---------------------------------------------------------------------------
// MFMA helpers.
// ---------------------------------------------------------------------------
__device__ __forceinline__ void load_w_swz(const u16* Wt, short* ws, int tid) {
  for (int c = tid; c < 2048; c += 256) {
    int n = c >> 4, kb = c & 15;
    short8 v = *reinterpret_cast<const short8*>(Wt + n * 128 + kb * 8);
    *reinterpret_cast<short8*>(ws + ((n << 4) | (kb ^ (n & 15))) * 8) = v;
  }
}
__device__ __forceinline__ half8 read_b_swz(const short* ws, int col, int kb) {
  short8 v = *reinterpret_cast<const short8*>(ws + ((col << 4) | (kb ^ (col & 15))) * 8);
  return __builtin_bit_cast(half8, v);
}
__device__ __forceinline__ void gemm_global(f32x4* acc, const u16* X, long arow,
                                            bool active, const short* wbuf,
                                            int nl, int q) {
#pragma unroll
  for (int s = 0; s < 4; ++s) {
    int kofs = s * 32 + q * 8, kb = (s << 2) | q;
    half8 a = half8{0,0,0,0,0,0,0,0};
    if (active)
      a = __builtin_bit_cast(half8,
          *reinterpret_cast<const short8*>(X + arow * 128 + kofs));
#pragma unroll
    for (int c = 0; c < 8; ++c) {
      half8 b = read_b_swz(wbuf, (c << 4) | nl, kb);
      acc[c] = __builtin_amdgcn_mfma_f32_16x16x32_f16(a, b, acc[c], 0, 0, 0);
    }
  }
}
__device__ __forceinline__ void gemm_tile(f32x4* acc, const short* mytile,
                                          const short* wbuf, int nl, int q) {
#pragma unroll
  for (int s = 0; s < 4; ++s) {
    int kofs = s * 32 + q * 8, kb = (s << 2) | q;
    half8 a = __builtin_bit_cast(half8,
        *reinterpret_cast<const short8*>(&mytile[nl * 136 + kofs]));
#pragma unroll
    for (int c = 0; c < 8; ++c) {
      half8 b = read_b_swz(wbuf, (c << 4) | nl, kb);
      acc[c] = __builtin_amdgcn_mfma_f32_16x16x32_f16(a, b, acc[c], 0, 0, 0);
    }
  }
}
__device__ __forceinline__ void zero_acc(f32x4* acc) {
#pragma unroll
  for (int c = 0; c < 8; ++c) acc[c] = f32x4{0.f, 0.f, 0.f, 0.f};
}

// ---------------------------------------------------------------------------
// Persistent layer: weights staged ONCE per block, then barrier-free loop
// over 64-row chunks. In-place safe.
// ---------------------------------------------------------------------------
template<bool DUAL, bool ACT>
__global__ __launch_bounds__(256) void layer_kernel(
    const u16* X, const u16* X2,
    const u16* __restrict__ W1t, const u16* __restrict__ W2t,
    const float* __restrict__ bias, u16* Y)
{
  __shared__ __align__(16) short w1s[16384];
  __shared__ __align__(16) short w2s[DUAL ? 16384 : 8];
  __shared__ float bs[128];
  int tid = threadIdx.x;
  load_w_swz(W1t, w1s, tid);
  if constexpr (DUAL) load_w_swz(W2t, w2s, tid);
  if (tid < 128) bs[tid] = bias[tid];
  __syncthreads();

  int wv = tid >> 6, lane = tid & 63, nl = lane & 15, q = lane >> 4;
  for (int ch = blockIdx.x; ch < NCHUNK; ch += gridDim.x) {
    long r0 = (long)ch * 64 + wv * 16;
    if (r0 >= NROWS) continue;
    long arow = r0 + nl;
    f32x4 acc[8];
    zero_acc(acc);
    gemm_global(acc, X, arow, true, w1s, nl, q);
    if constexpr (DUAL) gemm_global(acc, X2, arow, true, w2s, nl, q);
#pragma unroll
    for (int c = 0; c < 8; ++c) {
      float bv = bs[(c << 4) | nl];
#pragma unroll
      for (int r = 0; r < 4; ++r) {
        float o = acc[c][r] + bv;
        if constexpr (ACT) o = eluf(o);
        Y[(r0 + q * 4 + r) * 128 + ((c << 4) | nl)] = f2h_bits(o);
      }
    }
  }
}

// ---------------------------------------------------------------------------
// Persistent mlp_face.
// ---------------------------------------------------------------------------
__global__ __launch_bounds__(256) void mlp_face_kernel(
    const float* __restrict__ hv, const float* __restrict__ w0,
    const float* __restrict__ b0, const u16* __restrict__ w1t,
    const float* __restrict__ b1, u16* ff)
{
  __shared__ __align__(16) short w1s[16384];
  __shared__ __align__(16) short act0[64 * 136];
  __shared__ float hvs[448];
  __shared__ float w0s[896];
  __shared__ float b0s[128];
  __shared__ float b1s[128];
  int tid = threadIdx.x;
  load_w_swz(w1t, w1s, tid);
  for (int i = tid; i < 896; i += 256) w0s[i] = w0[i];
  if (tid < 128) { b0s[tid] = b0[tid]; b1s[tid] = b1[tid]; }
  int wv = tid >> 6, lane = tid & 63, nl = lane & 15, q = lane >> 4;

  for (int ch = blockIdx.x; ch < NCHUNK; ch += gridDim.x) {
    long base = (long)ch * 64;
    __syncthreads();                       // protect hvs/act0 reuse
    for (int i = tid; i < 448; i += 256) {
      long g = base * 7 + i;
      hvs[i] = (g < (long)NROWS * 7) ? hv[g] : 0.0f;
    }
    __syncthreads();
    for (int idx = tid; idx < 8192; idx += 256) {
      int n = idx >> 7, c = idx & 127;
      float s = b0s[c];
#pragma unroll
      for (int k = 0; k < 7; ++k) s += hvs[n * 7 + k] * w0s[k * 128 + c];
      act0[n * 136 + c] = (short)f2h_bits(eluf(s));
    }
    __syncthreads();
    long r0 = base + wv * 16;
    if (r0 >= NROWS) continue;
    f32x4 acc[8];
    zero_acc(acc);
    gemm_tile(acc, &act0[(wv * 16) * 136], w1s, nl, q);
#pragma unroll
    for (int c = 0; c < 8; ++c) {
      float bv = b1s[(c << 4) | nl];
#pragma unroll
      for (int r = 0; r < 4; ++r)
        ff[(r0 + q * 4 + r) * 128 + ((c << 4) | nl)] = f2h_bits(eluf(acc[c][r] + bv));
    }
  }
}

// ---------------------------------------------------------------------------
// Persistent final.
// ---------------------------------------------------------------------------
__global__ __launch_bounds__(256) void final_kernel(
    const u16* __restrict__ x, const float* __restrict__ w2,
    const float* __restrict__ b2, float* __restrict__ out)
{
  __shared__ float w2s[256];
  __shared__ float b2s[2];
  int tid = threadIdx.x;
  w2s[tid] = w2[tid];
  if (tid < 2) b2s[tid] = b2[tid];
  __syncthreads();
  for (int ch = blockIdx.x; ch < NCHUNK; ch += gridDim.x) {
    long node = (long)ch * 64 + (tid >> 2);
    int q = tid & 3;
    if (node >= NROWS) continue;
    const u16* xr = x + node * 128 + q * 32;
    float p0 = 0.f, p1 = 0.f;
#pragma unroll
    for (int i = 0; i < 4; ++i) {
      short8 v = *reinterpret_cast<const short8*>(xr + i * 8);
#pragma unroll
      for (int j = 0; j < 8; ++j) {
        float f = h2f((u16)v[j]);
        int cidx = q * 32 + i * 8 + j;
        p0 += f * w2s[cidx * 2];
        p1 += f * w2s[cidx * 2 + 1];
      }
    }
    p0 += __shfl_xor(p0, 1); p0 += __shfl_xor(p0, 2);
    p1 += __shfl_xor(p1, 1); p1 += __shfl_xor(p1, 2);
    if (q == 0) {
      out[node * 2]     = p0 + b2s[0];
      out[node * 2 + 1] = p1 + b2s[1];
    }
  }
}

// ---------------------------------------------------------------------------
extern "C" void kernel_launch(void* const* d_in, const int* in_sizes, int n_in,
                              void* d_out, int out_size, void* d_ws, size_t ws_size,
                              hipStream_t stream) {
  const float* hv        = (const float*)d_in[0];
  const int*   ei        = (const int*)d_in[1];
  const float* mf_w0     = (const float*)d_in[2];
  const float* mf_b0     = (const float*)d_in[3];
  const float* mf_w1     = (const float*)d_in[4];
  const float* mf_b1     = (const float*)d_in[5];
  const float* g1_rel_w  = (const float*)d_in[6];
  const float* g1_rel_b  = (const float*)d_in[7];
  const float* g1_root_w = (const float*)d_in[8];
  const float* g2_rel_w  = (const float*)d_in[9];
  const float* g2_rel_b  = (const float*)d_in[10];
  const float* g2_root_w = (const float*)d_in[11];
  const float* s1_w0     = (const float*)d_in[12];
  const float* s1_b0     = (const float*)d_in[13];
  const float* s1_w1     = (const float*)d_in[14];
  const float* s1_b1     = (const float*)d_in[15];
  const float* s1_w2     = (const float*)d_in[16];
  const float* s1_b2     = (const float*)d_in[17];
  const float* s2_w0     = (const float*)d_in[18];
  const float* s2_b0     = (const float*)d_in[19];
  const float* s2_w1     = (const float*)d_in[20];
  const float* s2_b1     = (const float*)d_in[21];
  const float* s2_w2     = (const float*)d_in[22];
  const float* s2_b2     = (const float*)d_in[23];

  constexpr size_t ACT_BYTES = (size_t)NROWS * 128 * 2;     // 128e6
  constexpr size_t ADJ_BYTES = (size_t)NEDGE * 4;           // 12e6
  constexpr size_t WT_BYTES  = 11 * 16384 * 2;              // 360,448
  constexpr size_t CSR_NEED  = 2 * ACT_BYTES + ADJ_BYTES + WT_BYTES + 4096;

  char* ws = (char*)d_ws;
  u16* A   = (u16*)ws;
  u16* G   = (u16*)(ws + ACT_BYTES);
  int* adj = (int*)(ws + 2 * ACT_BYTES);
  const bool CSRP = ws_size >= CSR_NEED;                    // 268,364,544

  u16* wT;
  int* bsum;
  int* cur;
  if (CSRP) {
    wT   = (u16*)(ws + 2 * ACT_BYTES + ADJ_BYTES);
    bsum = (int*)(ws + 2 * ACT_BYTES + ADJ_BYTES + WT_BYTES);
    cur  = (int*)d_out;   // consumed by gather2 before d_out written
  } else {
    wT   = (u16*)d_out;   // fallback stash (final reads only d_in)
    bsum = (int*)((char*)d_out + WT_BYTES);
    cur  = nullptr;
  }

  u16* mf_w1T   = wT + 0 * 16384;
  u16* g1_relT  = wT + 1 * 16384;
  u16* g1_rootT = wT + 2 * 16384;
  u16* s1_w0T   = wT + 3 * 16384;
  u16* s1_w1T   = wT + 4 * 16384;
  u16* s1_w2T   = wT + 5 * 16384;
  u16* g2_relT  = wT + 6 * 16384;
  u16* g2_rootT = wT + 7 * 16384;
  u16* s2w0loT  = wT + 8 * 16384;
  u16* s2w0hiT  = wT + 9 * 16384;
  u16* s2_w1T   = wT + 10 * 16384;

  transpose_w<<<dim3(8, 11), 256, 0, stream>>>(
      mf_w1, g1_rel_w, g1_root_w, s1_w0, s1_w1, s1_w2,
      g2_rel_w, g2_root_w, s2_w0, s2_w1, wT);

  // Persistent grids:
  const int gS = 1024;   // single-weight layer: ~33KB LDS -> 4 blocks/CU
  const int gD = 512;    // dual-weight layer:   ~65KB LDS -> 2 blocks/CU
  const int gM = 512;    // mlp_face:            ~56KB LDS -> 2 blocks/CU
  const int gF = 1024;   // final
  const int ge4 = (NEDGE / 4 + 255) / 256;  // 2930
  const int gn  = (NROWS + 3) / 4;          // 125000

  if (CSRP) {
    (void)hipMemsetAsync(cur, 0, (size_t)NROWS * 4, stream);
    hist_kernel<<<ge4, 256, 0, stream>>>(ei, cur);
    scanA<<<NBLK_SCAN, 256, 0, stream>>>(cur, bsum);
    scanB<<<1, 512, 0, stream>>>(bsum);
    scanC<<<NBLK_SCAN, 256, 0, stream>>>(bsum, cur);
    fill_kernel<<<ge4, 256, 0, stream>>>(ei, cur, adj);     // cur -> end offs

    mlp_face_kernel<<<gM, 256, 0, stream>>>(hv, mf_w0, mf_b0, mf_w1T, mf_b1, A); // A=ff
    gather_agg<<<gn, 256, 0, stream>>>(A, cur, adj, G);                           // G=agg1
    layer_kernel<true,  true ><<<gD, 256, 0, stream>>>(G, A, g1_relT, g1_rootT, g1_rel_b, A); // A=h
    layer_kernel<false, true ><<<gS, 256, 0, stream>>>(A, nullptr, s1_w0T, nullptr, s1_b0, A);
    layer_kernel<false, true ><<<gS, 256, 0, stream>>>(A, nullptr, s1_w1T, nullptr, s1_b1, A);
    layer_kernel<false, true ><<<gS, 256, 0, stream>>>(A, nullptr, s1_w2T, nullptr, s1_b2, A);
    gather_agg<<<gn, 256, 0, stream>>>(A, cur, adj, G);                           // G=agg2
    layer_kernel<true,  false><<<gD, 256, 0, stream>>>(G, A, g2_relT, g2_rootT, g2_rel_b, A); // A=h2
    mlp_face_kernel<<<gM, 256, 0, stream>>>(hv, mf_w0, mf_b0, mf_w1T, mf_b1, G);  // G=ff
    layer_kernel<true,  true ><<<gD, 256, 0, stream>>>(G, A, s2w0loT, s2w0hiT, s2_b0, G);
    layer_kernel<false, true ><<<gS, 256, 0, stream>>>(G, nullptr, s2_w1T, nullptr, s2_b1, G);
    final_kernel<<<gF, 256, 0, stream>>>(G, s2_w2, s2_b2, (float*)d_out);
  } else {
    mlp_face_kernel<<<gM, 256, 0, stream>>>(hv, mf_w0, mf_b0, mf_w1T, mf_b1, A);
    (void)hipMemsetAsync(G, 0, ACT_BYTES, stream);
    scatter_kernel<<<4096, 256, 0, stream>>>(A, ei, (__half2*)G);
    layer_kernel<true,  true ><<<gD, 256, 0, stream>>>(G, A, g1_relT, g1_rootT, g1_rel_b, A);
    layer_kernel<false, true ><<<gS, 256, 0, stream>>>(A, nullptr, s1_w0T, nullptr, s1_b0, A);
    layer_kernel<false, true ><<<gS, 256, 0, stream>>>(A, nullptr, s1_w1T, nullptr, s1_b1, A);
    layer_kernel<false, true ><<<gS, 256, 0, stream>>>(A, nullptr, s1_w2T, nullptr, s1_b2, A);
    (void)hipMemsetAsync(G, 0, ACT_BYTES, stream);
    scatter_kernel<<<4096, 256, 0, stream>>>(A, ei, (__half2*)G);
    layer_kernel<true,  false><<<gD, 256, 0, stream>>>(G, A, g2_relT, g2_rootT, g2_rel_b, A);
    mlp_face_kernel<<<gM, 256, 0, stream>>>(hv, mf_w0, mf_b0, mf_w1T, mf_b1, G);
    layer_kernel<true,  true ><<<gD, 256, 0, stream>>>(G, A, s2w0loT, s2w0hiT, s2_b0, G);
    layer_kernel<false, true ><<<gS, 256, 0, stream>>>(G, nullptr, s2_w1T, nullptr, s2_b1, G);
    final_kernel<<<gF, 256, 0, stream>>>(G, s2_w2, s2_b2, (float*)d_out);
  }
}

// Round 11
// 1444.966 us; speedup vs baseline: 1.5474x; 1.2068x over previous
//
#include <hip/hip_runtime.h>
#include <hip/hip_bf16.h>
#include <hip/hip_fp16.h>
#include <type_traits>
#include <utility>

// FaceModel: N=500000 nodes, E=3000000 edges, F=128. fp32 in/out, f16 internal.
// R11: CSR build rewritten as 2-stage counting sort. R10 showed atomicExch
// does NOT avoid dirty-line amplification (fill WRITE 187MB for 12MB adj,
// ~285us): random 4B writes always cost a 64B line once the footprint
// exceeds per-XCD L2. Fix: stage1 partitions edges into 489 coarse buckets
// (dst>>10) writing packed (local_dst<<19|src) into BLOCK-EXCLUSIVE
// contiguous runs (L2-resident -> ~1.3x amp); stage2 sorts each bucket in
// LDS and writes cur + adj coalesced. Gathers/layers unchanged from R10.

#define NROWS 500000
#define NEDGE 3000000
#define NCHUNK ((NROWS + 63) / 64)          // 7813
#define NBKT 489                             // ceil(NROWS/1024)
#define BSTR 16                              // padded int stride (64B) for bucket arrays

typedef unsigned short u16;
using short8 = __attribute__((ext_vector_type(8))) short;
using half8  = __attribute__((ext_vector_type(8))) _Float16;
using f32x4  = __attribute__((ext_vector_type(4))) float;

__device__ __forceinline__ u16 f2h_bits(float f) {
  _Float16 h = (_Float16)f;
  return __builtin_bit_cast(u16, h);
}
__device__ __forceinline__ float h2f(u16 b) {
  return (float)__builtin_bit_cast(_Float16, b);
}
__device__ __forceinline__ float eluf(float x) { return x > 0.0f ? x : expm1f(x); }

// --- f16 packed atomic add with fallback (scatter fallback path only) ------
template <typename T, typename = void> struct HasUnsafeAdd : std::false_type {};
template <typename T>
struct HasUnsafeAdd<T, std::void_t<decltype(unsafeAtomicAdd(
    std::declval<T*>(), std::declval<T>()))>> : std::true_type {};
template <bool HAS> struct AtomAdd;
template <> struct AtomAdd<true> {
  template <class T> __device__ static void go(T* p, T v) { unsafeAtomicAdd(p, v); }
};
template <> struct AtomAdd<false> {
  template <class T> __device__ static void go(T* p, T v) {
    unsigned* up = reinterpret_cast<unsigned*>(p);
    unsigned old = *up;
    while (true) {
      unsigned assumed = old;
      T cur = __builtin_bit_cast(T, assumed);
      T nw = __hadd2(cur, v);
      old = atomicCAS(up, assumed, __builtin_bit_cast(unsigned, nw));
      if (old == assumed) break;
    }
  }
};
__device__ __forceinline__ void atomAddH2(__half2* p, __half2 v) {
  AtomAdd<HasUnsafeAdd<__half2>::value>::go(p, v);
}

// ---------------------------------------------------------------------------
// Weight transpose fp32 -> f16 stash: out[slot][n*128+k] = W[k][n].
// Slots: 0 mf_w1, 1 g1_rel, 2 g1_root, 3 s1_w0, 4 s1_w1, 5 s1_w2,
//        6 g2_rel, 7 g2_root, 8 s2_w0[0:128], 9 s2_w0[128:256], 10 s2_w1
// ---------------------------------------------------------------------------
__global__ __launch_bounds__(256) void transpose_w(
    const float* p0, const float* p1, const float* p2, const float* p3,
    const float* p4, const float* p5, const float* p6, const float* p7,
    const float* p8, const float* p10, u16* dst)
{
  const float* src = p0; int eoff = 0;
  switch (blockIdx.y) {
    case 1: src = p1; break;  case 2: src = p2; break;
    case 3: src = p3; break;  case 4: src = p4; break;
    case 5: src = p5; break;  case 6: src = p6; break;
    case 7: src = p7; break;  case 8: src = p8; break;
    case 9: src = p8; eoff = 16384; break;
    case 10: src = p10; break;
    default: break;
  }
  u16* out = dst + (size_t)blockIdx.y * 16384;
  for (int i = threadIdx.x + blockIdx.x * 256; i < 16384; i += 2048) {
    int n = i >> 7, k = i & 127;
    out[i] = f2h_bits(src[eoff + k * 128 + n]);
  }
}

// ---------------------------------------------------------------------------
// Stage 0: bucket histogram (LDS pre-aggregated) into padded gbaseP.
// ---------------------------------------------------------------------------
__global__ __launch_bounds__(256) void bucket_hist(const int* __restrict__ ei,
                                                   int* __restrict__ gbaseP) {
  __shared__ int cnt[512];
  int tid = threadIdx.x;
  for (int i = tid; i < 512; i += 256) cnt[i] = 0;
  __syncthreads();
  long e0 = (long)blockIdx.x * 8192;
  int n = (int)min((long)8192, (long)NEDGE - e0);
  for (int i = tid; i < n; i += 256) atomicAdd(&cnt[ei[NEDGE + e0 + i] >> 10], 1);
  __syncthreads();
  for (int b = tid; b < NBKT; b += 256)
    if (cnt[b]) atomicAdd(&gbaseP[b * BSTR], cnt[b]);
}

// Counts -> exclusive bucket offsets; init allocation cursors.
__global__ __launch_bounds__(512) void bucket_scan(int* gbaseP, int* gcurP) {
  __shared__ int sd[512];
  int tid = threadIdx.x;
  int v = (tid < NBKT) ? gbaseP[tid * BSTR] : 0;
  sd[tid] = v;
  __syncthreads();
  for (int off = 1; off < 512; off <<= 1) {
    int val = (tid >= off) ? sd[tid - off] : 0;
    __syncthreads();
    sd[tid] += val;
    __syncthreads();
  }
  int excl = sd[tid] - v;
  if (tid < NBKT) { gbaseP[tid * BSTR] = excl; gcurP[tid * BSTR] = excl; }
  if (tid == 0) gbaseP[NBKT * BSTR] = NEDGE;
}

// ---------------------------------------------------------------------------
// Stage 1: partition edges into bucket runs. Per 8192-edge tile: LDS count,
// one global reservation atomic per (tile,bucket), then write packed
// (local_dst<<19)|src into the block-exclusive contiguous run.
// ---------------------------------------------------------------------------
__global__ __launch_bounds__(256) void partition_kernel(
    const int* __restrict__ ei, int* __restrict__ gcurP, int* __restrict__ adj)
{
  __shared__ int cnt[512], cnt2[512], rsv[512];
  int tid = threadIdx.x;
  for (int i = tid; i < 512; i += 256) { cnt[i] = 0; cnt2[i] = 0; }
  __syncthreads();
  long e0 = (long)blockIdx.x * 8192;
  int n = (int)min((long)8192, (long)NEDGE - e0);
  for (int i = tid; i < n; i += 256) atomicAdd(&cnt[ei[NEDGE + e0 + i] >> 10], 1);
  __syncthreads();
  for (int b = tid; b < NBKT; b += 256) {
    int c = cnt[b];
    rsv[b] = c ? atomicAdd(&gcurP[b * BSTR], c) : 0;
  }
  __syncthreads();
  for (int i = tid; i < n; i += 256) {
    int d = ei[NEDGE + e0 + i], s = ei[e0 + i];
    int b = d >> 10;
    int r = atomicAdd(&cnt2[b], 1);
    adj[rsv[b] + r] = ((d & 1023) << 19) | s;
  }
}

// ---------------------------------------------------------------------------
// Stage 2: sort one bucket per block. Load packed slice into LDS (in-place
// safe: fully read before written), per-node histogram + scan, write cur
// (end offsets) and node-sorted srcs back -- all coalesced.
// Oversized (>8192, never for uniform graph) streams via global scratch.
// ---------------------------------------------------------------------------
__global__ __launch_bounds__(256) void bucket_sort(
    const int* __restrict__ gbaseP, int* adj, int* __restrict__ cur,
    int* __restrict__ scratch)
{
  __shared__ __align__(16) int pk[8192];
  __shared__ __align__(16) int outb[8192];
  __shared__ int cnts[1024];
  __shared__ int base[1024];
  __shared__ int sd[256];
  int tid = threadIdx.x, b = blockIdx.x;
  int beg = gbaseP[b * BSTR], end = gbaseP[(b + 1) * BSTR];
  int cnt = end - beg;
  int n0 = b << 10;
  int nn = min(1024, NROWS - n0);
  bool fits = (cnt <= 8192);

  if (fits) {
    for (int i = tid; i < cnt; i += 256) pk[i] = adj[beg + i];
  } else {
    for (int i = tid; i < cnt; i += 256) scratch[beg + i] = adj[beg + i];
  }
  for (int i = tid; i < 1024; i += 256) cnts[i] = 0;
  __syncthreads();

  if (fits) {
    for (int i = tid; i < cnt; i += 256) atomicAdd(&cnts[pk[i] >> 19], 1);
  } else {
    for (int i = tid; i < cnt; i += 256) atomicAdd(&cnts[scratch[beg + i] >> 19], 1);
  }
  __syncthreads();

  // scan 1024 counters (4/thread), write cur = beg + inclusive end
  int l0 = cnts[tid * 4], l1 = cnts[tid * 4 + 1],
      l2 = cnts[tid * 4 + 2], l3 = cnts[tid * 4 + 3];
  int p = l0 + l1 + l2 + l3;
  sd[tid] = p;
  __syncthreads();
  for (int off = 1; off < 256; off <<= 1) {
    int val = (tid >= off) ? sd[tid - off] : 0;
    __syncthreads();
    sd[tid] += val;
    __syncthreads();
  }
  int excl = sd[tid] - p;
  int lv[4] = {l0, l1, l2, l3};
#pragma unroll
  for (int k = 0; k < 4; ++k) {
    int node = tid * 4 + k;
    base[node] = excl;
    excl += lv[k];
    if (node < nn) cur[n0 + node] = beg + excl;
  }
  __syncthreads();
  for (int i = tid; i < 1024; i += 256) cnts[i] = 0;   // reuse as rank
  __syncthreads();

  if (fits) {
    for (int i = tid; i < cnt; i += 256) {
      int v = pk[i];
      int ld = v >> 19;
      int r = atomicAdd(&cnts[ld], 1);
      outb[base[ld] + r] = v & 0x7FFFF;
    }
    __syncthreads();
    for (int i = tid; i < cnt; i += 256) adj[beg + i] = outb[i];
  } else {
    for (int i = tid; i < cnt; i += 256) {
      int v = scratch[beg + i];
      int ld = v >> 19;
      int r = atomicAdd(&cnts[ld], 1);
      adj[beg + base[ld] + r] = v & 0x7FFFF;
    }
  }
}

// ---------------------------------------------------------------------------
// Gather segment-sum: wave per node, 8 rows batched, fp32 accumulate.
// ---------------------------------------------------------------------------
__global__ __launch_bounds__(256) void gather_agg(
    const u16* __restrict__ x, const int* __restrict__ cend,
    const int* __restrict__ adj, u16* __restrict__ agg)
{
  int wv = threadIdx.x >> 6, lane = threadIdx.x & 63;
  long node = (long)blockIdx.x * 4 + wv;
  if (node >= NROWS) return;
  int beg = (node == 0) ? 0 : cend[node - 1];
  int end = cend[node];
  float a0 = 0.f, a1 = 0.f;
  for (int j = beg; j < end; j += 8) {
    int take = end - j;
    if (take > 8) take = 8;
    int srcv = (lane < take) ? adj[j + lane] : 0;
    unsigned hb[8];
#pragma unroll
    for (int t = 0; t < 8; ++t) {
      if (t < take) {
        int src = __shfl(srcv, t);
        hb[t] = *reinterpret_cast<const unsigned*>(x + (long)src * 128 + lane * 2);
      }
    }
#pragma unroll
    for (int t = 0; t < 8; ++t) {
      if (t < take) {
        __half2 h = __builtin_bit_cast(__half2, hb[t]);
        a0 += (float)h.x;
        a1 += (float)h.y;
      }
    }
  }
  __half2 r;
  r.x = __float2half(a0);
  r.y = __float2half(a1);
  *reinterpret_cast<__half2*>(agg + node * 128 + lane * 2) = r;
}

// ---------------------------------------------------------------------------
// Atomic scatter (fallback path only).
// ---------------------------------------------------------------------------
__global__ __launch_bounds__(256) void scatter_kernel(
    const u16* __restrict__ x, const int* __restrict__ ei,
    __half2* __restrict__ agg)
{
  int gtid = blockIdx.x * 256 + threadIdx.x;
  int wid = gtid >> 6, lane = gtid & 63;
  int nw = gridDim.x * 4;
  for (int e = wid; e < NEDGE; e += nw) {
    int s = ei[e];
    int d = ei[NEDGE + e];
    __half2 h = *reinterpret_cast<const __half2*>(x + (long)s * 128 + lane * 2);
    atomAddH2(agg + (long)d * 64 + lane, h);
  }
}

// ---------------------------------------------------------------------------
// MFMA helpers.
// ---------------------------------------------------------------------------
__device__ __forceinline__ void load_w_swz(const u16* Wt, short* ws, int tid) {
  for (int c = tid; c < 2048; c += 256) {
    int n = c >> 4, kb = c & 15;
    short8 v = *reinterpret_cast<const short8*>(Wt + n * 128 + kb * 8);
    *reinterpret_cast<short8*>(ws + ((n << 4) | (kb ^ (n & 15))) * 8) = v;
  }
}
__device__ __forceinline__ half8 read_b_swz(const short* ws, int col, int kb) {
  short8 v = *reinterpret_cast<const short8*>(ws + ((col << 4) | (kb ^ (col & 15))) * 8);
  return __builtin_bit_cast(half8, v);
}
__device__ __forceinline__ void gemm_global(f32x4* acc, const u16* X, long arow,
                                            bool active, const short* wbuf,
                                            int nl, int q) {
#pragma unroll
  for (int s = 0; s < 4; ++s) {
    int kofs = s * 32 + q * 8, kb = (s << 2) | q;
    half8 a = half8{0,0,0,0,0,0,0,0};
    if (active)
      a = __builtin_bit_cast(half8,
          *reinterpret_cast<const short8*>(X + arow * 128 + kofs));
#pragma unroll
    for (int c = 0; c < 8; ++c) {
      half8 b = read_b_swz(wbuf, (c << 4) | nl, kb);
      acc[c] = __builtin_amdgcn_mfma_f32_16x16x32_f16(a, b, acc[c], 0, 0, 0);
    }
  }
}
__device__ __forceinline__ void gemm_tile(f32x4* acc, const short* mytile,
                                          const short* wbuf, int nl, int q) {
#pragma unroll
  for (int s = 0; s < 4; ++s) {
    int kofs = s * 32 + q * 8, kb = (s << 2) | q;
    half8 a = __builtin_bit_cast(half8,
        *reinterpret_cast<const short8*>(&mytile[nl * 136 + kofs]));
#pragma unroll
    for (int c = 0; c < 8; ++c) {
      half8 b = read_b_swz(wbuf, (c << 4) | nl, kb);
      acc[c] = __builtin_amdgcn_mfma_f32_16x16x32_f16(a, b, acc[c], 0, 0, 0);
    }
  }
}
__device__ __forceinline__ void zero_acc(f32x4* acc) {
#pragma unroll
  for (int c = 0; c < 8; ++c) acc[c] = f32x4{0.f, 0.f, 0.f, 0.f};
}

// ---------------------------------------------------------------------------
// Persistent layer: weights staged ONCE per block, then barrier-free loop
// over 64-row chunks. In-place safe.
// ---------------------------------------------------------------------------
template<bool DUAL, bool ACT>
__global__ __launch_bounds__(256) void layer_kernel(
    const u16* X, const u16* X2,
    const u16* __restrict__ W1t, const u16* __restrict__ W2t,
    const float* __restrict__ bias, u16* Y)
{
  __shared__ __align__(16) short w1s[16384];
  __shared__ __align__(16) short w2s[DUAL ? 16384 : 8];
  __shared__ float bs[128];
  int tid = threadIdx.x;
  load_w_swz(W1t, w1s, tid);
  if constexpr (DUAL) load_w_swz(W2t, w2s, tid);
  if (tid < 128) bs[tid] = bias[tid];
  __syncthreads();

  int wv = tid >> 6, lane = tid & 63, nl = lane & 15, q = lane >> 4;
  for (int ch = blockIdx.x; ch < NCHUNK; ch += gridDim.x) {
    long r0 = (long)ch * 64 + wv * 16;
    if (r0 >= NROWS) continue;
    long arow = r0 + nl;
    f32x4 acc[8];
    zero_acc(acc);
    gemm_global(acc, X, arow, true, w1s, nl, q);
    if constexpr (DUAL) gemm_global(acc, X2, arow, true, w2s, nl, q);
#pragma unroll
    for (int c = 0; c < 8; ++c) {
      float bv = bs[(c << 4) | nl];
#pragma unroll
      for (int r = 0; r < 4; ++r) {
        float o = acc[c][r] + bv;
        if constexpr (ACT) o = eluf(o);
        Y[(r0 + q * 4 + r) * 128 + ((c << 4) | nl)] = f2h_bits(o);
      }
    }
  }
}

// ---------------------------------------------------------------------------
// Persistent mlp_face.
// ---------------------------------------------------------------------------
__global__ __launch_bounds__(256) void mlp_face_kernel(
    const float* __restrict__ hv, const float* __restrict__ w0,
    const float* __restrict__ b0, const u16* __restrict__ w1t,
    const float* __restrict__ b1, u16* ff)
{
  __shared__ __align__(16) short w1s[16384];
  __shared__ __align__(16) short act0[64 * 136];
  __shared__ float hvs[448];
  __shared__ float w0s[896];
  __shared__ float b0s[128];
  __shared__ float b1s[128];
  int tid = threadIdx.x;
  load_w_swz(w1t, w1s, tid);
  for (int i = tid; i < 896; i += 256) w0s[i] = w0[i];
  if (tid < 128) { b0s[tid] = b0[tid]; b1s[tid] = b1[tid]; }
  int wv = tid >> 6, lane = tid & 63, nl = lane & 15, q = lane >> 4;

  for (int ch = blockIdx.x; ch < NCHUNK; ch += gridDim.x) {
    long base = (long)ch * 64;
    __syncthreads();                       // protect hvs/act0 reuse
    for (int i = tid; i < 448; i += 256) {
      long g = base * 7 + i;
      hvs[i] = (g < (long)NROWS * 7) ? hv[g] : 0.0f;
    }
    __syncthreads();
    for (int idx = tid; idx < 8192; idx += 256) {
      int n = idx >> 7, c = idx & 127;
      float s = b0s[c];
#pragma unroll
      for (int k = 0; k < 7; ++k) s += hvs[n * 7 + k] * w0s[k * 128 + c];
      act0[n * 136 + c] = (short)f2h_bits(eluf(s));
    }
    __syncthreads();
    long r0 = base + wv * 16;
    if (r0 >= NROWS) continue;
    f32x4 acc[8];
    zero_acc(acc);
    gemm_tile(acc, &act0[(wv * 16) * 136], w1s, nl, q);
#pragma unroll
    for (int c = 0; c < 8; ++c) {
      float bv = b1s[(c << 4) | nl];
#pragma unroll
      for (int r = 0; r < 4; ++r)
        ff[(r0 + q * 4 + r) * 128 + ((c << 4) | nl)] = f2h_bits(eluf(acc[c][r] + bv));
    }
  }
}

// ---------------------------------------------------------------------------
// Persistent final.
// ---------------------------------------------------------------------------
__global__ __launch_bounds__(256) void final_kernel(
    const u16* __restrict__ x, const float* __restrict__ w2,
    const float* __restrict__ b2, float* __restrict__ out)
{
  __shared__ float w2s[256];
  __shared__ float b2s[2];
  int tid = threadIdx.x;
  w2s[tid] = w2[tid];
  if (tid < 2) b2s[tid] = b2[tid];
  __syncthreads();
  for (int ch = blockIdx.x; ch < NCHUNK; ch += gridDim.x) {
    long node = (long)ch * 64 + (tid >> 2);
    int q = tid & 3;
    if (node >= NROWS) continue;
    const u16* xr = x + node * 128 + q * 32;
    float p0 = 0.f, p1 = 0.f;
#pragma unroll
    for (int i = 0; i < 4; ++i) {
      short8 v = *reinterpret_cast<const short8*>(xr + i * 8);
#pragma unroll
      for (int j = 0; j < 8; ++j) {
        float f = h2f((u16)v[j]);
        int cidx = q * 32 + i * 8 + j;
        p0 += f * w2s[cidx * 2];
        p1 += f * w2s[cidx * 2 + 1];
      }
    }
    p0 += __shfl_xor(p0, 1); p0 += __shfl_xor(p0, 2);
    p1 += __shfl_xor(p1, 1); p1 += __shfl_xor(p1, 2);
    if (q == 0) {
      out[node * 2]     = p0 + b2s[0];
      out[node * 2 + 1] = p1 + b2s[1];
    }
  }
}

// ---------------------------------------------------------------------------
extern "C" void kernel_launch(void* const* d_in, const int* in_sizes, int n_in,
                              void* d_out, int out_size, void* d_ws, size_t ws_size,
                              hipStream_t stream) {
  const float* hv        = (const float*)d_in[0];
  const int*   ei        = (const int*)d_in[1];
  const float* mf_w0     = (const float*)d_in[2];
  const float* mf_b0     = (const float*)d_in[3];
  const float* mf_w1     = (const float*)d_in[4];
  const float* mf_b1     = (const float*)d_in[5];
  const float* g1_rel_w  = (const float*)d_in[6];
  const float* g1_rel_b  = (const float*)d_in[7];
  const float* g1_root_w = (const float*)d_in[8];
  const float* g2_rel_w  = (const float*)d_in[9];
  const float* g2_rel_b  = (const float*)d_in[10];
  const float* g2_root_w = (const float*)d_in[11];
  const float* s1_w0     = (const float*)d_in[12];
  const float* s1_b0     = (const float*)d_in[13];
  const float* s1_w1     = (const float*)d_in[14];
  const float* s1_b1     = (const float*)d_in[15];
  const float* s1_w2     = (const float*)d_in[16];
  const float* s1_b2     = (const float*)d_in[17];
  const float* s2_w0     = (const float*)d_in[18];
  const float* s2_b0     = (const float*)d_in[19];
  const float* s2_w1     = (const float*)d_in[20];
  const float* s2_b1     = (const float*)d_in[21];
  const float* s2_w2     = (const float*)d_in[22];
  const float* s2_b2     = (const float*)d_in[23];

  constexpr size_t ACT_BYTES = (size_t)NROWS * 128 * 2;     // 128e6
  constexpr size_t ADJ_BYTES = (size_t)NEDGE * 4;           // 12e6
  constexpr size_t WT_BYTES  = 11 * 16384 * 2;              // 360,448
  constexpr size_t CSR_NEED  = 2 * ACT_BYTES + ADJ_BYTES + WT_BYTES + 4096;

  char* ws = (char*)d_ws;
  u16* A   = (u16*)ws;
  u16* G   = (u16*)(ws + ACT_BYTES);
  int* adj = (int*)(ws + 2 * ACT_BYTES);
  const bool CSRP = ws_size >= CSR_NEED;                    // 268,364,544

  u16* wT;
  int* cur;     // per-node end offsets (2e6 B)
  int* gbaseP;  // padded bucket offsets ((NBKT+1)*64 B)
  int* gcurP;   // padded bucket cursors (NBKT*64 B)
  if (CSRP) {
    wT     = (u16*)(ws + 2 * ACT_BYTES + ADJ_BYTES);
    cur    = (int*)d_out;                                   // consumed pre-final
    gbaseP = (int*)((char*)d_out + 2000000);
    gcurP  = (int*)((char*)d_out + 2000000 + (NBKT + 1) * 64);
  } else {
    wT     = (u16*)d_out;   // fallback stash (final reads only d_in)
    cur    = nullptr; gbaseP = nullptr; gcurP = nullptr;
  }

  u16* mf_w1T   = wT + 0 * 16384;
  u16* g1_relT  = wT + 1 * 16384;
  u16* g1_rootT = wT + 2 * 16384;
  u16* s1_w0T   = wT + 3 * 16384;
  u16* s1_w1T   = wT + 4 * 16384;
  u16* s1_w2T   = wT + 5 * 16384;
  u16* g2_relT  = wT + 6 * 16384;
  u16* g2_rootT = wT + 7 * 16384;
  u16* s2w0loT  = wT + 8 * 16384;
  u16* s2w0hiT  = wT + 9 * 16384;
  u16* s2_w1T   = wT + 10 * 16384;

  transpose_w<<<dim3(8, 11), 256, 0, stream>>>(
      mf_w1, g1_rel_w, g1_root_w, s1_w0, s1_w1, s1_w2,
      g2_rel_w, g2_root_w, s2_w0, s2_w1, wT);

  // Persistent grids:
  const int gS = 1024;   // single-weight layer: ~33KB LDS -> 4 blocks/CU
  const int gD = 512;    // dual-weight layer:   ~65KB LDS -> 2 blocks/CU
  const int gM = 512;    // mlp_face:            ~56KB LDS -> 2 blocks/CU
  const int gF = 1024;   // final
  const int gT = (NEDGE + 8191) / 8192;     // 367 edge tiles
  const int gn = (NROWS + 3) / 4;           // 125000

  if (CSRP) {
    // ---- CSR via 2-stage counting sort ----
    (void)hipMemsetAsync(gbaseP, 0, (size_t)(2 * NBKT + 1) * 64, stream);
    bucket_hist<<<gT, 256, 0, stream>>>(ei, gbaseP);
    bucket_scan<<<1, 512, 0, stream>>>(gbaseP, gcurP);
    partition_kernel<<<gT, 256, 0, stream>>>(ei, gcurP, adj);
    bucket_sort<<<NBKT, 256, 0, stream>>>(gbaseP, adj, cur, (int*)G);

    mlp_face_kernel<<<gM, 256, 0, stream>>>(hv, mf_w0, mf_b0, mf_w1T, mf_b1, A); // A=ff
    gather_agg<<<gn, 256, 0, stream>>>(A, cur, adj, G);                           // G=agg1
    layer_kernel<true,  true ><<<gD, 256, 0, stream>>>(G, A, g1_relT, g1_rootT, g1_rel_b, A); // A=h
    layer_kernel<false, true ><<<gS, 256, 0, stream>>>(A, nullptr, s1_w0T, nullptr, s1_b0, A);
    layer_kernel<false, true ><<<gS, 256, 0, stream>>>(A, nullptr, s1_w1T, nullptr, s1_b1, A);
    layer_kernel<false, true ><<<gS, 256, 0, stream>>>(A, nullptr, s1_w2T, nullptr, s1_b2, A);
    gather_agg<<<gn, 256, 0, stream>>>(A, cur, adj, G);                           // G=agg2
    layer_kernel<true,  false><<<gD, 256, 0, stream>>>(G, A, g2_relT, g2_rootT, g2_rel_b, A); // A=h2
    mlp_face_kernel<<<gM, 256, 0, stream>>>(hv, mf_w0, mf_b0, mf_w1T, mf_b1, G);  // G=ff
    layer_kernel<true,  true ><<<gD, 256, 0, stream>>>(G, A, s2w0loT, s2w0hiT, s2_b0, G);
    layer_kernel<false, true ><<<gS, 256, 0, stream>>>(G, nullptr, s2_w1T, nullptr, s2_b1, G);
    final_kernel<<<gF, 256, 0, stream>>>(G, s2_w2, s2_b2, (float*)d_out);
  } else {
    mlp_face_kernel<<<gM, 256, 0, stream>>>(hv, mf_w0, mf_b0, mf_w1T, mf_b1, A);
    (void)hipMemsetAsync(G, 0, ACT_BYTES, stream);
    scatter_kernel<<<4096, 256, 0, stream>>>(A, ei, (__half2*)G);
    layer_kernel<true,  true ><<<gD, 256, 0, stream>>>(G, A, g1_relT, g1_rootT, g1_rel_b, A);
    layer_kernel<false, true ><<<gS, 256, 0, stream>>>(A, nullptr, s1_w0T, nullptr, s1_b0, A);
    layer_kernel<false, true ><<<gS, 256, 0, stream>>>(A, nullptr, s1_w1T, nullptr, s1_b1, A);
    layer_kernel<false, true ><<<gS, 256, 0, stream>>>(A, nullptr, s1_w2T, nullptr, s1_b2, A);
    (void)hipMemsetAsync(G, 0, ACT_BYTES, stream);
    scatter_kernel<<<4096, 256, 0, stream>>>(A, ei, (__half2*)G);
    layer_kernel<true,  false><<<gD, 256, 0, stream>>>(G, A, g2_relT, g2_rootT, g2_rel_b, A);
    mlp_face_kernel<<<gM, 256, 0, stream>>>(hv, mf_w0, mf_b0, mf_w1T, mf_b1, G);
    layer_kernel<true,  true ><<<gD, 256, 0, stream>>>(G, A, s2w0loT, s2w0hiT, s2_b0, G);
    layer_kernel<false, true ><<<gS, 256, 0, stream>>>(G, nullptr, s2_w1T, nullptr, s2_b1, G);
    final_kernel<<<gF, 256, 0, stream>>>(G, s2_w2, s2_b2, (float*)d_out);
  }
}